// Round 1
// baseline (1108.285 us; speedup 1.0000x reference)
//
#include <hip/hip_runtime.h>
#include <hip/hip_bf16.h>
#include <math.h>

#define N 4096
#define E_EDGES 32768
#define IN_DIM 1024
#define DM 192
#define DI 384
#define DS 16
#define DC 4
#define DTR 12
#define NSEQ 8
#define NCHUNK 64
#define CHL (N / NCHUNK)   /* 64 */
#define EPSG 1e-7f
#define LN_EPS 1e-5f

__device__ __forceinline__ float siluf(float x){ return x / (1.f + __expf(-x)); }
__device__ __forceinline__ float softplusf_(float x){ return (x > 20.f) ? x : log1pf(__expf(x)); }
__device__ __forceinline__ unsigned fenc(float f){ unsigned u = __float_as_uint(f); return (u & 0x80000000u) ? ~u : (u | 0x80000000u); }
__device__ __forceinline__ float fdec(unsigned u){ return (u & 0x80000000u) ? __uint_as_float(u ^ 0x80000000u) : __uint_as_float(~u); }

// ---------------- init ----------------
__global__ void k_init(float* __restrict__ ysum, unsigned* __restrict__ mxe,
                       float* __restrict__ den, float* __restrict__ aggr,
                       float* __restrict__ pooled){
  int i = blockIdx.x * blockDim.x + threadIdx.x;
  if (i < N * DI) ysum[i] = 0.f;
  if (i < N * DM){ mxe[i] = 0x007FFFFFu; den[i] = 0.f; aggr[i] = 0.f; }
  if (i < DM) pooled[i] = 0.f;
}

// ---------------- feature transform: h = relu(x @ ft_w^T + ft_b) ----------------
#define FT_ROWS 8
__global__ __launch_bounds__(192) void k_ft(const float* __restrict__ x, const float* __restrict__ w,
                                            const float* __restrict__ b, float* __restrict__ h){
  __shared__ float xs[FT_ROWS][IN_DIM];
  int n0 = blockIdx.x * FT_ROWS;
  int tid = threadIdx.x;
  const float4* xv = (const float4*)(x + (size_t)n0 * IN_DIM);
  float4* sv = (float4*)&xs[0][0];
  for (int i = tid; i < FT_ROWS * IN_DIM / 4; i += 192) sv[i] = xv[i];
  __syncthreads();
  int d = tid;
  float acc[FT_ROWS];
#pragma unroll
  for (int m = 0; m < FT_ROWS; m++) acc[m] = 0.f;
  const float* wr = w + (size_t)d * IN_DIM;
  for (int k = 0; k < IN_DIM; k += 4){
    float4 wv = *(const float4*)(wr + k);
#pragma unroll
    for (int m = 0; m < FT_ROWS; m++){
      float4 q = *(const float4*)(&xs[m][k]);
      acc[m] += wv.x*q.x + wv.y*q.y + wv.z*q.z + wv.w*q.w;
    }
  }
  float bb = b[d];
#pragma unroll
  for (int m = 0; m < FT_ROWS; m++){
    float v = acc[m] + bb;
    h[(size_t)(n0 + m) * DM + d] = v > 0.f ? v : 0.f;
  }
}

// ---------------- generic row LayerNorm (one wave per row) ----------------
__global__ __launch_bounds__(64) void k_ln(const float* __restrict__ in, const float* __restrict__ g,
                                           const float* __restrict__ b, float* __restrict__ out, int D){
  int n = blockIdx.x, lane = threadIdx.x;
  const float* r = in + (size_t)n * D;
  float s = 0.f;
  for (int i = lane; i < D; i += 64) s += r[i];
#pragma unroll
  for (int o = 32; o > 0; o >>= 1) s += __shfl_down(s, o);
  s = __shfl(s, 0);
  float mean = s / D;
  float v = 0.f;
  for (int i = lane; i < D; i += 64){ float t = r[i] - mean; v += t * t; }
#pragma unroll
  for (int o = 32; o > 0; o >>= 1) v += __shfl_down(v, o);
  v = __shfl(v, 0) / D;
  float rs = rsqrtf(v + LN_EPS);
  for (int i = lane; i < D; i += 64) out[(size_t)n * D + i] = (r[i] - mean) * rs * g[i] + b[i];
}

// ---------------- in_proj: xz = hn @ in_proj_w^T  (xi | z) ----------------
#define IP_ROWS 8
__global__ __launch_bounds__(256) void k_inproj(const float* __restrict__ hn, const float* __restrict__ w,
                                                float* __restrict__ xi, float* __restrict__ z){
  __shared__ float s[IP_ROWS][DM];
  int n0 = blockIdx.x * IP_ROWS, tid = threadIdx.x;
  for (int i = tid; i < IP_ROWS * DM; i += 256) s[i / DM][i % DM] = hn[(size_t)n0 * DM + i];
  __syncthreads();
  for (int j = tid; j < 2 * DI; j += 256){
    const float* wr = w + (size_t)j * DM;
    float acc[IP_ROWS];
#pragma unroll
    for (int m = 0; m < IP_ROWS; m++) acc[m] = 0.f;
    for (int k = 0; k < DM; k += 4){
      float4 wv = *(const float4*)(wr + k);
#pragma unroll
      for (int m = 0; m < IP_ROWS; m++){
        float4 q = *(const float4*)(&s[m][k]);
        acc[m] += wv.x*q.x + wv.y*q.y + wv.z*q.z + wv.w*q.w;
      }
    }
#pragma unroll
    for (int m = 0; m < IP_ROWS; m++){
      int n = n0 + m;
      if (j < DI) xi[(size_t)n * DI + j] = acc[m];
      else        z [(size_t)n * DI + (j - DI)] = acc[m];
    }
  }
}

// ---------------- stage A: gather + conv + silu + x_proj ----------------
#define SA_TN 16
__global__ __launch_bounds__(256) void k_stagea(const float* __restrict__ xi,
    const int* __restrict__ p1, const int* __restrict__ p2, const int* __restrict__ p3,
    const float* __restrict__ conv_w, const float* __restrict__ conv_b,
    const float* __restrict__ xpw,
    float* __restrict__ xc_all, float* __restrict__ dtin_all,
    float* __restrict__ B_all, float* __restrict__ C_all){
  int s = blockIdx.y;
  int n0 = blockIdx.x * SA_TN;
  int tid = threadIdx.x;
  int pi = s >> 1, rev = s & 1;
  const int* perm = (pi == 1) ? p1 : (pi == 2) ? p2 : (pi == 3) ? p3 : nullptr;
  __shared__ float xg[SA_TN + 3][DI];
  __shared__ float xcs[SA_TN][DI];
  for (int i = tid; i < (SA_TN + 3) * DI; i += 256){
    int r = i / DI, d = i % DI;
    int n = n0 - 3 + r;
    float v = 0.f;
    if (n >= 0){
      int pos = rev ? (N - 1 - n) : n;
      int src = perm ? perm[pos] : pos;
      v = xi[(size_t)src * DI + d];
    }
    xg[r][d] = v;
  }
  __syncthreads();
  for (int i = tid; i < SA_TN * DI; i += 256){
    int m = i / DI, d = i % DI;
    float acc = conv_b[d];
#pragma unroll
    for (int k = 0; k < DC; k++) acc += xg[m + k][d] * conv_w[d * DC + k];
    float v = siluf(acc);
    xcs[m][d] = v;
    xc_all[((size_t)s * N + (n0 + m)) * DI + d] = v;
  }
  __syncthreads();
  for (int o = tid; o < SA_TN * (DTR + 2 * DS); o += 256){
    int m = o / (DTR + 2 * DS), j = o % (DTR + 2 * DS);
    const float* wr = xpw + (size_t)j * DI;
    float acc = 0.f;
    for (int k = 0; k < DI; k += 4){
      float4 wv = *(const float4*)(wr + k);
      float4 q = *(const float4*)(&xcs[m][k]);
      acc += wv.x*q.x + wv.y*q.y + wv.z*q.z + wv.w*q.w;
    }
    int n = n0 + m;
    if (j < DTR)            dtin_all[((size_t)s * N + n) * DTR + j] = acc;
    else if (j < DTR + DS)  B_all[((size_t)s * N + n) * DS + (j - DTR)] = acc;
    else                    C_all[((size_t)s * N + n) * DS + (j - DTR - DS)] = acc;
  }
}

// ---------------- scan pass 1: per-chunk (P, F) ----------------
__global__ __launch_bounds__(384) void k_pass1(
    const float* __restrict__ xc_all, const float* __restrict__ dtin_all,
    const float* __restrict__ B_all, const float* __restrict__ A_log,
    const float* __restrict__ dtw, const float* __restrict__ dtb,
    float* __restrict__ P, float* __restrict__ F){
  int s = blockIdx.y, c = blockIdx.x;
  int d = threadIdx.x;
  __shared__ float sB[CHL][DS];
  __shared__ float sdt[CHL][DTR];
  int n0 = c * CHL;
  for (int i = d; i < CHL * DS; i += 384) sB[i / DS][i % DS] = B_all[((size_t)s * N + n0) * DS + i];
  for (int i = d; i < CHL * DTR; i += 384) sdt[i / DTR][i % DTR] = dtin_all[((size_t)s * N + n0) * DTR + i];
  __syncthreads();
  float eA[DS], wdt[DTR];
#pragma unroll
  for (int k = 0; k < DS; k++) eA[k] = -__expf(A_log[d * DS + k]);
#pragma unroll
  for (int r = 0; r < DTR; r++) wdt[r] = dtw[d * DTR + r];
  float bdt = dtb[d];
  float Pr[DS], Fr[DS];
#pragma unroll
  for (int k = 0; k < DS; k++){ Pr[k] = 1.f; Fr[k] = 0.f; }
  const float* xcb = xc_all + ((size_t)s * N + n0) * DI + d;
  for (int t = 0; t < CHL; t++){
    float din = bdt;
#pragma unroll
    for (int r = 0; r < DTR; r++) din += sdt[t][r] * wdt[r];
    float dt = softplusf_(din);
    float xc = xcb[(size_t)t * DI];
    float bc = dt * xc;
#pragma unroll
    for (int k = 0; k < DS; k++){
      float a = __expf(dt * eA[k]);
      Pr[k] *= a;
      Fr[k] = Fr[k] * a + bc * sB[t][k];
    }
  }
  size_t base = (((size_t)s * NCHUNK + c) * DI + d) * DS;
#pragma unroll
  for (int k = 0; k < DS; k++){ P[base + k] = Pr[k]; F[base + k] = Fr[k]; }
}

// ---------------- scan pass 2: combine chunk boundaries ----------------
__global__ void k_pass2(const float* __restrict__ P, const float* __restrict__ F, float* __restrict__ Hinit){
  int gi = blockIdx.x * blockDim.x + threadIdx.x;
  if (gi >= NSEQ * DI * DS) return;
  int s = gi / (DI * DS), i = gi % (DI * DS);
  float H = 0.f;
  for (int c = 0; c < NCHUNK; c++){
    size_t o = ((size_t)s * NCHUNK + c) * (DI * DS) + i;
    Hinit[o] = H;
    H = F[o] + P[o] * H;
  }
}

// ---------------- scan pass 3: replay + y scatter ----------------
__global__ __launch_bounds__(384) void k_pass3(
    const float* __restrict__ xc_all, const float* __restrict__ dtin_all,
    const float* __restrict__ B_all, const float* __restrict__ C_all,
    const float* __restrict__ A_log, const float* __restrict__ dtw, const float* __restrict__ dtb,
    const float* __restrict__ Dp, const float* __restrict__ Hinit,
    const int* __restrict__ p1, const int* __restrict__ p2, const int* __restrict__ p3,
    float* __restrict__ ysum){
  int s = blockIdx.y, c = blockIdx.x;
  int d = threadIdx.x;
  int pi = s >> 1, rev = s & 1;
  const int* perm = (pi == 1) ? p1 : (pi == 2) ? p2 : (pi == 3) ? p3 : nullptr;
  __shared__ float sB[CHL][DS];
  __shared__ float sC[CHL][DS];
  __shared__ float sdt[CHL][DTR];
  __shared__ int sorig[CHL];
  int n0 = c * CHL;
  for (int i = d; i < CHL * DS; i += 384){
    sB[i / DS][i % DS] = B_all[((size_t)s * N + n0) * DS + i];
    sC[i / DS][i % DS] = C_all[((size_t)s * N + n0) * DS + i];
  }
  for (int i = d; i < CHL * DTR; i += 384) sdt[i / DTR][i % DTR] = dtin_all[((size_t)s * N + n0) * DTR + i];
  for (int t = d; t < CHL; t += 384){
    int n = n0 + t;
    int pos = rev ? (N - 1 - n) : n;
    sorig[t] = perm ? perm[pos] : pos;
  }
  __syncthreads();
  float eA[DS], wdt[DTR];
#pragma unroll
  for (int k = 0; k < DS; k++) eA[k] = -__expf(A_log[d * DS + k]);
#pragma unroll
  for (int r = 0; r < DTR; r++) wdt[r] = dtw[d * DTR + r];
  float bdt = dtb[d];
  float Dpd = Dp[d];
  float hreg[DS];
  size_t hb = (((size_t)s * NCHUNK + c) * DI + d) * DS;
#pragma unroll
  for (int k = 0; k < DS; k++) hreg[k] = Hinit[hb + k];
  const float* xcb = xc_all + ((size_t)s * N + n0) * DI + d;
  for (int t = 0; t < CHL; t++){
    float din = bdt;
#pragma unroll
    for (int r = 0; r < DTR; r++) din += sdt[t][r] * wdt[r];
    float dt = softplusf_(din);
    float xc = xcb[(size_t)t * DI];
    float bc = dt * xc;
    float y = 0.f;
#pragma unroll
    for (int k = 0; k < DS; k++){
      float a = __expf(dt * eA[k]);
      hreg[k] = hreg[k] * a + bc * sB[t][k];
      y += hreg[k] * sC[t][k];
    }
    y += xc * Dpd;
    atomicAdd(&ysum[(size_t)sorig[t] * DI + d], y * 0.125f);
  }
}

// ---------------- g = y_sum * silu(z) ----------------
__global__ void k_gmul(const float* __restrict__ ys, const float* __restrict__ z, float* __restrict__ g){
  int i = blockIdx.x * blockDim.x + threadIdx.x;
  if (i < N * DI){ float zz = z[i]; g[i] = ys[i] * siluf(zz); }
}

// ---------------- out_proj: h2 = g @ out_proj_w^T ----------------
__global__ __launch_bounds__(192) void k_outproj(const float* __restrict__ g, const float* __restrict__ w,
                                                 float* __restrict__ h2){
  __shared__ float sg[8][DI];
  int n0 = blockIdx.x * 8, tid = threadIdx.x;
  for (int i = tid; i < 8 * DI; i += 192) sg[i / DI][i % DI] = g[(size_t)n0 * DI + i];
  __syncthreads();
  const float* wr = w + (size_t)tid * DI;
  float acc[8];
#pragma unroll
  for (int m = 0; m < 8; m++) acc[m] = 0.f;
  for (int k = 0; k < DI; k += 4){
    float4 wv = *(const float4*)(wr + k);
#pragma unroll
    for (int m = 0; m < 8; m++){
      float4 q = *(const float4*)(&sg[m][k]);
      acc[m] += wv.x*q.x + wv.y*q.y + wv.z*q.z + wv.w*q.w;
    }
  }
#pragma unroll
  for (int m = 0; m < 8; m++) h2[(size_t)(n0 + m) * DM + tid] = acc[m];
}

// ---------------- GNN edge kernels ----------------
__global__ void k_edge_max(const int* __restrict__ ei, const float* __restrict__ h2,
                           const float* __restrict__ gt, unsigned* __restrict__ mxe){
  int gi = blockIdx.x * blockDim.x + threadIdx.x;
  if (gi >= E_EDGES * DM) return;
  int e = gi / DM, dd = gi % DM;
  int src = ei[e], dst = ei[E_EDGES + e];
  float m = h2[(size_t)src * DM + dd]; m = (m > 0.f ? m : 0.f) + EPSG;
  float logit = gt[0] * m;
  atomicMax(&mxe[(size_t)dst * DM + dd], fenc(logit));
}

__global__ void k_mxfin(unsigned* __restrict__ mxe){
  int i = blockIdx.x * blockDim.x + threadIdx.x;
  if (i < N * DM){
    float f = fdec(mxe[i]);
    if (!isfinite(f)) f = 0.f;
    ((float*)mxe)[i] = f;
  }
}

__global__ void k_edge_den(const int* __restrict__ ei, const float* __restrict__ h2,
                           const float* __restrict__ gt, const float* __restrict__ mx,
                           float* __restrict__ den){
  int gi = blockIdx.x * blockDim.x + threadIdx.x;
  if (gi >= E_EDGES * DM) return;
  int e = gi / DM, dd = gi % DM;
  int src = ei[e], dst = ei[E_EDGES + e];
  float m = h2[(size_t)src * DM + dd]; m = (m > 0.f ? m : 0.f) + EPSG;
  float ex = __expf(gt[0] * m - mx[(size_t)dst * DM + dd]);
  atomicAdd(&den[(size_t)dst * DM + dd], ex);
}

__global__ void k_edge_aggr(const int* __restrict__ ei, const float* __restrict__ h2,
                            const float* __restrict__ gt, const float* __restrict__ mx,
                            const float* __restrict__ den, float* __restrict__ aggr){
  int gi = blockIdx.x * blockDim.x + threadIdx.x;
  if (gi >= E_EDGES * DM) return;
  int e = gi / DM, dd = gi % DM;
  int src = ei[e], dst = ei[E_EDGES + e];
  float m = h2[(size_t)src * DM + dd]; m = (m > 0.f ? m : 0.f) + EPSG;
  float ex = __expf(gt[0] * m - mx[(size_t)dst * DM + dd]);
  float dn = den[(size_t)dst * DM + dd];
  float alpha = ex / (dn > 0.f ? dn : 1.f);
  atomicAdd(&aggr[(size_t)dst * DM + dd], alpha * m);
}

// ---------------- mlp1: u2 = relu(ln((aggr+h2) @ mlp1^T + b)) ----------------
__global__ __launch_bounds__(384) void k_mlp1(const float* __restrict__ aggr, const float* __restrict__ h2,
    const float* __restrict__ w, const float* __restrict__ b,
    const float* __restrict__ lg, const float* __restrict__ lb, float* __restrict__ u2){
  __shared__ float su[DM];
  __shared__ float rbuf[6];
  int n = blockIdx.x, tid = threadIdx.x;
  for (int i = tid; i < DM; i += 384) su[i] = aggr[(size_t)n * DM + i] + h2[(size_t)n * DM + i];
  __syncthreads();
  const float* wr = w + (size_t)tid * DM;
  float acc = b[tid];
  for (int k = 0; k < DM; k += 4){
    float4 wv = *(const float4*)(wr + k);
    float4 q = *(const float4*)(&su[k]);
    acc += wv.x*q.x + wv.y*q.y + wv.z*q.z + wv.w*q.w;
  }
  float s1 = acc;
#pragma unroll
  for (int o = 32; o > 0; o >>= 1) s1 += __shfl_down(s1, o);
  if ((tid & 63) == 0) rbuf[tid >> 6] = s1;
  __syncthreads();
  float mean = (rbuf[0]+rbuf[1]+rbuf[2]+rbuf[3]+rbuf[4]+rbuf[5]) / DI;
  __syncthreads();
  float dv = acc - mean, s2 = dv * dv;
#pragma unroll
  for (int o = 32; o > 0; o >>= 1) s2 += __shfl_down(s2, o);
  if ((tid & 63) == 0) rbuf[tid >> 6] = s2;
  __syncthreads();
  float var = (rbuf[0]+rbuf[1]+rbuf[2]+rbuf[3]+rbuf[4]+rbuf[5]) / DI;
  float v = dv * rsqrtf(var + LN_EPS) * lg[tid] + lb[tid];
  u2[(size_t)n * DI + tid] = v > 0.f ? v : 0.f;
}

// ---------------- mlp2 + res + res + final LN ----------------
__global__ __launch_bounds__(192) void k_mlp2(const float* __restrict__ u2, const float* __restrict__ w,
    const float* __restrict__ b, const float* __restrict__ gg, const float* __restrict__ gb,
    const float* __restrict__ h2, const float* __restrict__ hres,
    const float* __restrict__ ng, const float* __restrict__ nb, float* __restrict__ hn2){
  __shared__ float su[DI];
  __shared__ float rbuf[3];
  int n = blockIdx.x, tid = threadIdx.x;
  for (int i = tid; i < DI; i += 192) su[i] = u2[(size_t)n * DI + i];
  __syncthreads();
  const float* wr = w + (size_t)tid * DI;
  float acc = b[tid];
  for (int k = 0; k < DI; k += 4){
    float4 wv = *(const float4*)(wr + k);
    float4 q = *(const float4*)(&su[k]);
    acc += wv.x*q.x + wv.y*q.y + wv.z*q.z + wv.w*q.w;
  }
  float s1 = acc;
#pragma unroll
  for (int o = 32; o > 0; o >>= 1) s1 += __shfl_down(s1, o);
  if ((tid & 63) == 0) rbuf[tid >> 6] = s1;
  __syncthreads();
  float mean = (rbuf[0] + rbuf[1] + rbuf[2]) / DM;
  __syncthreads();
  float dv = acc - mean, s2 = dv * dv;
#pragma unroll
  for (int o = 32; o > 0; o >>= 1) s2 += __shfl_down(s2, o);
  if ((tid & 63) == 0) rbuf[tid >> 6] = s2;
  __syncthreads();
  float var = (rbuf[0] + rbuf[1] + rbuf[2]) / DM;
  float r = dv * rsqrtf(var + LN_EPS) * gg[tid] + gb[tid];
  r = r > 0.f ? r : 0.f;
  float h4 = h2[(size_t)n * DM + tid] + r + hres[(size_t)n * DM + tid];
  __syncthreads();
  float t1 = h4;
#pragma unroll
  for (int o = 32; o > 0; o >>= 1) t1 += __shfl_down(t1, o);
  if ((tid & 63) == 0) rbuf[tid >> 6] = t1;
  __syncthreads();
  float m2 = (rbuf[0] + rbuf[1] + rbuf[2]) / DM;
  __syncthreads();
  float dv2 = h4 - m2, t2 = dv2 * dv2;
#pragma unroll
  for (int o = 32; o > 0; o >>= 1) t2 += __shfl_down(t2, o);
  if ((tid & 63) == 0) rbuf[tid >> 6] = t2;
  __syncthreads();
  float v2 = (rbuf[0] + rbuf[1] + rbuf[2]) / DM;
  hn2[(size_t)n * DM + tid] = dv2 * rsqrtf(v2 + LN_EPS) * ng[tid] + nb[tid];
}

// ---------------- attention score ----------------
__global__ __launch_bounds__(128) void k_attn(const float* __restrict__ hn2, const float* __restrict__ w1,
    const float* __restrict__ b1, const float* __restrict__ w2, const float* __restrict__ b2,
    float* __restrict__ a){
  __shared__ float sh[DM];
  __shared__ float rr[2];
  int n = blockIdx.x, tid = threadIdx.x;
  for (int i = tid; i < DM; i += 128) sh[i] = hn2[(size_t)n * DM + i];
  __syncthreads();
  const float* wr = w1 + (size_t)tid * DM;
  float acc = b1[tid];
  for (int k = 0; k < DM; k += 4){
    float4 wv = *(const float4*)(wr + k);
    float4 q = *(const float4*)(&sh[k]);
    acc += wv.x*q.x + wv.y*q.y + wv.z*q.z + wv.w*q.w;
  }
  float t = tanhf(acc) * w2[tid];
#pragma unroll
  for (int o = 32; o > 0; o >>= 1) t += __shfl_down(t, o);
  if ((tid & 63) == 0) rr[tid >> 6] = t;
  __syncthreads();
  if (tid == 0) a[n] = rr[0] + rr[1] + b2[0];
}

// ---------------- softmax over a[N] (in place -> weights) ----------------
__global__ __launch_bounds__(1024) void k_softmax(float* __restrict__ a){
  int tid = threadIdx.x;
  __shared__ float rb[16];
  float mx = -1e30f;
  for (int i = tid; i < N; i += 1024) mx = fmaxf(mx, a[i]);
#pragma unroll
  for (int o = 32; o > 0; o >>= 1) mx = fmaxf(mx, __shfl_down(mx, o));
  if ((tid & 63) == 0) rb[tid >> 6] = mx;
  __syncthreads();
  float m = -1e30f;
  for (int i = 0; i < 16; i++) m = fmaxf(m, rb[i]);
  __syncthreads();
  float z = 0.f;
  for (int i = tid; i < N; i += 1024) z += __expf(a[i] - m);
#pragma unroll
  for (int o = 32; o > 0; o >>= 1) z += __shfl_down(z, o);
  if ((tid & 63) == 0) rb[tid >> 6] = z;
  __syncthreads();
  float Z = 0.f;
  for (int i = 0; i < 16; i++) Z += rb[i];
  float inv = 1.f / Z;
  for (int i = tid; i < N; i += 1024) a[i] = __expf(a[i] - m) * inv;
}

// ---------------- weighted pool ----------------
__global__ __launch_bounds__(192) void k_pool(const float* __restrict__ wgt, const float* __restrict__ hn2,
                                              float* __restrict__ pooled){
  int bidx = blockIdx.x, d = threadIdx.x;
  float acc = 0.f;
  for (int r = 0; r < 128; r++){
    int n = bidx * 128 + r;
    acc += wgt[n] * hn2[(size_t)n * DM + d];
  }
  atomicAdd(&pooled[d], acc);
}

// ---------------- head ----------------
__global__ __launch_bounds__(64) void k_head(const float* __restrict__ pooled, const float* __restrict__ hw,
                                             const float* __restrict__ hb, float* __restrict__ out){
  int tid = threadIdx.x;
  for (int c = 0; c < 2; c++){
    float s = 0.f;
    for (int d = tid; d < DM; d += 64) s += pooled[d] * hw[c * DM + d];
#pragma unroll
    for (int o = 32; o > 0; o >>= 1) s += __shfl_down(s, o);
    if (tid == 0) out[c] = s + hb[c];
  }
}

extern "C" void kernel_launch(void* const* d_in, const int* in_sizes, int n_in,
                              void* d_out, int out_size, void* d_ws, size_t ws_size,
                              hipStream_t stream){
  (void)in_sizes; (void)n_in; (void)out_size; (void)ws_size;
  const float* x        = (const float*)d_in[0];
  const int*   ei       = (const int*)d_in[1];
  const int*   perm_pre = (const int*)d_in[2];
  const int*   perm_post= (const int*)d_in[3];
  const int*   perm_lvl = (const int*)d_in[4];
  const float* ft_w     = (const float*)d_in[5];
  const float* ft_b     = (const float*)d_in[6];
  const float* ln1_g    = (const float*)d_in[7];
  const float* ln1_b    = (const float*)d_in[8];
  const float* in_proj_w= (const float*)d_in[9];
  const float* conv_w   = (const float*)d_in[10];
  const float* conv_b   = (const float*)d_in[11];
  const float* x_proj_w = (const float*)d_in[12];
  const float* dt_proj_w= (const float*)d_in[13];
  const float* dt_proj_b= (const float*)d_in[14];
  const float* A_log    = (const float*)d_in[15];
  const float* D_param  = (const float*)d_in[16];
  const float* out_proj_w=(const float*)d_in[17];
  const float* gnn_t    = (const float*)d_in[18];
  const float* mlp1_w   = (const float*)d_in[19];
  const float* mlp1_b   = (const float*)d_in[20];
  const float* mlp_ln_g = (const float*)d_in[21];
  const float* mlp_ln_b = (const float*)d_in[22];
  const float* mlp2_w   = (const float*)d_in[23];
  const float* mlp2_b   = (const float*)d_in[24];
  const float* gnn_g    = (const float*)d_in[25];
  const float* gnn_b    = (const float*)d_in[26];
  const float* norm_g   = (const float*)d_in[27];
  const float* norm_b   = (const float*)d_in[28];
  const float* attn1_w  = (const float*)d_in[29];
  const float* attn1_b  = (const float*)d_in[30];
  const float* attn2_w  = (const float*)d_in[31];
  const float* attn2_b  = (const float*)d_in[32];
  const float* head_w   = (const float*)d_in[33];
  const float* head_b   = (const float*)d_in[34];

  float* ws = (float*)d_ws;
  size_t off = 0;
  float* h      = ws + off; off += (size_t)N * DM;
  float* hn     = ws + off; off += (size_t)N * DM;
  float* xi     = ws + off; off += (size_t)N * DI;
  float* z      = ws + off; off += (size_t)N * DI;
  float* xc_all = ws + off; off += (size_t)NSEQ * N * DI;
  float* dtin   = ws + off; off += (size_t)NSEQ * N * DTR;
  float* Ball   = ws + off; off += (size_t)NSEQ * N * DS;
  float* Call   = ws + off; off += (size_t)NSEQ * N * DS;
  float* Pb     = ws + off; off += (size_t)NSEQ * NCHUNK * DI * DS;
  float* Fb     = ws + off; off += (size_t)NSEQ * NCHUNK * DI * DS;
  float* Hin    = ws + off; off += (size_t)NSEQ * NCHUNK * DI * DS;
  float* ysum   = ws + off; off += (size_t)N * DI;
  float* g      = ws + off; off += (size_t)N * DI;
  float* h2     = ws + off; off += (size_t)N * DM;
  float* mx     = ws + off; off += (size_t)N * DM;
  float* den    = ws + off; off += (size_t)N * DM;
  float* aggr   = ws + off; off += (size_t)N * DM;
  float* u2     = ws + off; off += (size_t)N * DI;
  float* hn2    = ws + off; off += (size_t)N * DM;
  float* ascore = ws + off; off += (size_t)N;
  float* pooled = ws + off; off += DM;

  k_init<<<dim3((N * DI + 255) / 256), dim3(256), 0, stream>>>(ysum, (unsigned*)mx, den, aggr, pooled);
  k_ft<<<dim3(N / FT_ROWS), dim3(192), 0, stream>>>(x, ft_w, ft_b, h);
  k_ln<<<dim3(N), dim3(64), 0, stream>>>(h, ln1_g, ln1_b, hn, DM);
  k_inproj<<<dim3(N / IP_ROWS), dim3(256), 0, stream>>>(hn, in_proj_w, xi, z);
  k_stagea<<<dim3(N / SA_TN, NSEQ), dim3(256), 0, stream>>>(xi, perm_pre, perm_post, perm_lvl,
      conv_w, conv_b, x_proj_w, xc_all, dtin, Ball, Call);
  k_pass1<<<dim3(NCHUNK, NSEQ), dim3(384), 0, stream>>>(xc_all, dtin, Ball, A_log, dt_proj_w, dt_proj_b, Pb, Fb);
  k_pass2<<<dim3((NSEQ * DI * DS + 255) / 256), dim3(256), 0, stream>>>(Pb, Fb, Hin);
  k_pass3<<<dim3(NCHUNK, NSEQ), dim3(384), 0, stream>>>(xc_all, dtin, Ball, Call, A_log, dt_proj_w, dt_proj_b,
      D_param, Hin, perm_pre, perm_post, perm_lvl, ysum);
  k_gmul<<<dim3((N * DI + 255) / 256), dim3(256), 0, stream>>>(ysum, z, g);
  k_outproj<<<dim3(N / 8), dim3(192), 0, stream>>>(g, out_proj_w, h2);
  k_edge_max<<<dim3((E_EDGES * DM + 255) / 256), dim3(256), 0, stream>>>(ei, h2, gnn_t, (unsigned*)mx);
  k_mxfin<<<dim3((N * DM + 255) / 256), dim3(256), 0, stream>>>((unsigned*)mx);
  k_edge_den<<<dim3((E_EDGES * DM + 255) / 256), dim3(256), 0, stream>>>(ei, h2, gnn_t, mx, den);
  k_edge_aggr<<<dim3((E_EDGES * DM + 255) / 256), dim3(256), 0, stream>>>(ei, h2, gnn_t, mx, den, aggr);
  k_mlp1<<<dim3(N), dim3(384), 0, stream>>>(aggr, h2, mlp1_w, mlp1_b, mlp_ln_g, mlp_ln_b, u2);
  k_mlp2<<<dim3(N), dim3(192), 0, stream>>>(u2, mlp2_w, mlp2_b, gnn_g, gnn_b, h2, h, norm_g, norm_b, hn2);
  k_attn<<<dim3(N), dim3(128), 0, stream>>>(hn2, attn1_w, attn1_b, attn2_w, attn2_b, ascore);
  k_softmax<<<dim3(1), dim3(1024), 0, stream>>>(ascore);
  k_pool<<<dim3(N / 128), dim3(192), 0, stream>>>(ascore, hn2, pooled);
  k_head<<<dim3(1), dim3(64), 0, stream>>>(pooled, head_w, head_b, (float*)d_out);
}

// Round 2
// 894.509 us; speedup vs baseline: 1.2390x; 1.2390x over previous
//
#include <hip/hip_runtime.h>
#include <hip/hip_bf16.h>
#include <math.h>

#define N 4096
#define E_EDGES 32768
#define IN_DIM 1024
#define DM 192
#define DI 384
#define DS 16
#define DC 4
#define DTR 12
#define NSEQ 8
#define NCHUNK 64
#define CHL (N / NCHUNK)   /* 64 */
#define EPSG 1e-7f
#define LN_EPS 1e-5f

__device__ __forceinline__ float siluf(float x){ return x / (1.f + __expf(-x)); }
__device__ __forceinline__ float softplusf_(float x){ return (x > 20.f) ? x : log1pf(__expf(x)); }
__device__ __forceinline__ unsigned fenc(float f){ unsigned u = __float_as_uint(f); return (u & 0x80000000u) ? ~u : (u | 0x80000000u); }
__device__ __forceinline__ float fdec(unsigned u){ return (u & 0x80000000u) ? __uint_as_float(u ^ 0x80000000u) : __uint_as_float(~u); }

// ---------------- init ----------------
__global__ void k_init(float* __restrict__ ysum, unsigned* __restrict__ mxe,
                       float* __restrict__ den, float* __restrict__ aggr,
                       float* __restrict__ pooled){
  int i = blockIdx.x * blockDim.x + threadIdx.x;
  if (i < N * DI) ysum[i] = 0.f;
  if (i < N * DM){ mxe[i] = 0x007FFFFFu; den[i] = 0.f; aggr[i] = 0.f; }
  if (i < DM) pooled[i] = 0.f;
}

// ---------------- feature transform + LN1 fused ----------------
// h = relu(x @ ft_w^T + b); hn = LN(h)
__global__ __launch_bounds__(256) void k_ft(const float* __restrict__ x, const float* __restrict__ w,
     const float* __restrict__ b, const float* __restrict__ lg, const float* __restrict__ lb,
     float* __restrict__ h, float* __restrict__ hn){
  __shared__ float xs[16 * IN_DIM];
  __shared__ float hs[16][DM];
  __shared__ float sm[16], sr[16];
  int n0 = blockIdx.x * 16, tid = threadIdx.x;
  { const float4* src = (const float4*)(x + (size_t)n0 * IN_DIM);
    float4* dst = (float4*)xs;
    for (int i = tid; i < 16 * IN_DIM / 4; i += 256) dst[i] = src[i]; }
  __syncthreads();
  int rg = tid >> 6;        // rows rg*4 .. +3
  int cg = tid & 63;        // cols cg*3 .. +2
  float acc[4][3] = {};
  for (int k = 0; k < IN_DIM; k += 4){
    float4 xv[4];
#pragma unroll
    for (int m = 0; m < 4; m++) xv[m] = *(const float4*)(xs + (rg*4+m)*IN_DIM + k);
#pragma unroll
    for (int c = 0; c < 3; c++){
      float4 wv = *(const float4*)(w + (size_t)(cg*3+c)*IN_DIM + k);
#pragma unroll
      for (int m = 0; m < 4; m++)
        acc[m][c] += wv.x*xv[m].x + wv.y*xv[m].y + wv.z*xv[m].z + wv.w*xv[m].w;
    }
  }
#pragma unroll
  for (int c = 0; c < 3; c++){
    float bb = b[cg*3+c];
#pragma unroll
    for (int m = 0; m < 4; m++){
      float v = acc[m][c] + bb; v = v > 0.f ? v : 0.f;
      hs[rg*4+m][cg*3+c] = v;
      h[(size_t)(n0+rg*4+m)*DM + cg*3+c] = v;
    }
  }
  __syncthreads();
  int lane = tid & 63;
#pragma unroll
  for (int q = 0; q < 4; q++){
    int r = rg*4 + q;
    float v0 = hs[r][lane], v1 = hs[r][64+lane], v2 = hs[r][128+lane];
    float s1 = v0+v1+v2, s2 = v0*v0+v1*v1+v2*v2;
#pragma unroll
    for (int o = 32; o > 0; o >>= 1){ s1 += __shfl_xor(s1,o); s2 += __shfl_xor(s2,o); }
    if (lane == 0){ float mean = s1/192.f; sm[r] = mean; sr[r] = rsqrtf(s2/192.f - mean*mean + LN_EPS); }
  }
  __syncthreads();
  for (int i = tid; i < 16*DM; i += 256){
    int r = i/DM, c = i%DM;
    hn[(size_t)(n0+r)*DM + c] = (hs[r][c]-sm[r])*sr[r]*lg[c] + lb[c];
  }
}

// ---------------- in_proj: xz = hn @ in_proj_w^T  (xi | z) ----------------
__global__ __launch_bounds__(256) void k_inproj(const float* __restrict__ hn, const float* __restrict__ w,
                                                float* __restrict__ xi, float* __restrict__ z){
  __shared__ float s[16 * DM];
  int n0 = blockIdx.x * 16, tid = threadIdx.x;
  { const float4* src = (const float4*)(hn + (size_t)n0 * DM);
    float4* dst = (float4*)s;
    for (int i = tid; i < 16 * DM / 4; i += 256) dst[i] = src[i]; }
  __syncthreads();
  int rg = tid >> 6, cg = tid & 63;   // cols cg*12 .. +11
  float acc[4][12] = {};
  for (int k = 0; k < DM; k += 4){
    float4 xv[4];
#pragma unroll
    for (int m = 0; m < 4; m++) xv[m] = *(const float4*)(s + (rg*4+m)*DM + k);
#pragma unroll
    for (int c = 0; c < 12; c++){
      float4 wv = *(const float4*)(w + (size_t)(cg*12+c)*DM + k);
#pragma unroll
      for (int m = 0; m < 4; m++)
        acc[m][c] += wv.x*xv[m].x + wv.y*xv[m].y + wv.z*xv[m].z + wv.w*xv[m].w;
    }
  }
#pragma unroll
  for (int m = 0; m < 4; m++){
    int n = n0 + rg*4 + m;
#pragma unroll
    for (int c = 0; c < 12; c++){
      int j = cg*12 + c;
      if (j < DI) xi[(size_t)n*DI + j] = acc[m][c];
      else        z [(size_t)n*DI + (j-DI)] = acc[m][c];
    }
  }
}

// ---------------- stage A: gather + conv + silu + x_proj (W in LDS, wave-per-8-rows) ----------------
__global__ __launch_bounds__(512) void k_stagea(const float* __restrict__ xi,
    const int* __restrict__ p1, const int* __restrict__ p2, const int* __restrict__ p3,
    const float* __restrict__ conv_w, const float* __restrict__ conv_b,
    const float* __restrict__ xpw,
    float* __restrict__ xc_all, float* __restrict__ dtin_all,
    float* __restrict__ B_all, float* __restrict__ C_all){
  __shared__ float sW[44 * DI];
  int s = blockIdx.y;
  int tid = threadIdx.x;
  { const float4* src = (const float4*)xpw;
    float4* dst = (float4*)sW;
    for (int i = tid; i < 44 * DI / 4; i += 512) dst[i] = src[i]; }
  int wid = tid >> 6, lane = tid & 63;
  int pi = s >> 1, rev = s & 1;
  const int* perm = (pi == 1) ? p1 : (pi == 2) ? p2 : (pi == 3) ? p3 : nullptr;
  int nbase = blockIdx.x * 64 + wid * 8;
  float4 cw[6]; float cb[6];
#pragma unroll
  for (int r = 0; r < 6; r++){
    int d = r*64 + lane;
    cw[r] = *(const float4*)(conv_w + d*DC);
    cb[r] = conv_b[d];
  }
  __syncthreads();
  // rolling 4-tap window of gathered xi rows (lane owns d = r*64+lane)
  float tap[4][6];
#pragma unroll
  for (int t = 0; t < 4; t++){
    int nn = nbase - 3 + t;
    if (nn >= 0){
      int pos = rev ? (N-1-nn) : nn;
      int srcr = perm ? perm[pos] : pos;
      const float* xr = xi + (size_t)srcr * DI;
#pragma unroll
      for (int r = 0; r < 6; r++) tap[t][r] = xr[r*64 + lane];
    } else {
#pragma unroll
      for (int r = 0; r < 6; r++) tap[t][r] = 0.f;
    }
  }
  float xv[8][6];
#pragma unroll
  for (int i = 0; i < 8; i++){
    int n = nbase + i;
#pragma unroll
    for (int r = 0; r < 6; r++){
      float a = cb[r] + tap[0][r]*cw[r].x + tap[1][r]*cw[r].y + tap[2][r]*cw[r].z + tap[3][r]*cw[r].w;
      xv[i][r] = siluf(a);
    }
    float* xo = xc_all + ((size_t)s*N + n)*DI;
#pragma unroll
    for (int r = 0; r < 6; r++) xo[r*64 + lane] = xv[i][r];
    if (i < 7){
#pragma unroll
      for (int t = 0; t < 3; t++)
#pragma unroll
        for (int r = 0; r < 6; r++) tap[t][r] = tap[t+1][r];
      int nn = n + 1;
      int pos = rev ? (N-1-nn) : nn;
      int srcr = perm ? perm[pos] : pos;
      const float* xr = xi + (size_t)srcr * DI;
#pragma unroll
      for (int r = 0; r < 6; r++) tap[3][r] = xr[r*64 + lane];
    }
  }
  // x_proj: 44 outputs per row; W rows from LDS reused across the 8 rows
  float outv[8];
  for (int j = 0; j < 44; j++){
    const float* wj = sW + j*DI;
    float w0 = wj[lane],      w1 = wj[64+lane],  w2 = wj[128+lane];
    float w3 = wj[192+lane],  w4 = wj[256+lane], w5 = wj[320+lane];
#pragma unroll
    for (int i = 0; i < 8; i++){
      float p = xv[i][0]*w0 + xv[i][1]*w1 + xv[i][2]*w2
              + xv[i][3]*w3 + xv[i][4]*w4 + xv[i][5]*w5;
#pragma unroll
      for (int o = 32; o > 0; o >>= 1) p += __shfl_xor(p, o);
      if (lane == j) outv[i] = p;
    }
  }
#pragma unroll
  for (int i = 0; i < 8; i++){
    size_t base = (size_t)s*N + (nbase + i);
    if (lane < DTR)              dtin_all[base*DTR + lane] = outv[i];
    else if (lane < DTR+DS)      B_all[base*DS + (lane-DTR)] = outv[i];
    else if (lane < DTR+2*DS)    C_all[base*DS + (lane-DTR-DS)] = outv[i];
  }
}

// ---------------- scan pass 1: per-chunk (P, F) ----------------
__global__ __launch_bounds__(384) void k_pass1(
    const float* __restrict__ xc_all, const float* __restrict__ dtin_all,
    const float* __restrict__ B_all, const float* __restrict__ A_log,
    const float* __restrict__ dtw, const float* __restrict__ dtb,
    float* __restrict__ P, float* __restrict__ F){
  int s = blockIdx.y, c = blockIdx.x;
  int d = threadIdx.x;
  __shared__ float sB[CHL][DS];
  __shared__ float sdt[CHL][DTR];
  int n0 = c * CHL;
  for (int i = d; i < CHL * DS; i += 384) sB[i / DS][i % DS] = B_all[((size_t)s * N + n0) * DS + i];
  for (int i = d; i < CHL * DTR; i += 384) sdt[i / DTR][i % DTR] = dtin_all[((size_t)s * N + n0) * DTR + i];
  __syncthreads();
  float eA[DS], wdt[DTR];
#pragma unroll
  for (int k = 0; k < DS; k++) eA[k] = -__expf(A_log[d * DS + k]);
#pragma unroll
  for (int r = 0; r < DTR; r++) wdt[r] = dtw[d * DTR + r];
  float bdt = dtb[d];
  float Pr[DS], Fr[DS];
#pragma unroll
  for (int k = 0; k < DS; k++){ Pr[k] = 1.f; Fr[k] = 0.f; }
  const float* xcb = xc_all + ((size_t)s * N + n0) * DI + d;
  for (int t = 0; t < CHL; t++){
    float din = bdt;
#pragma unroll
    for (int r = 0; r < DTR; r++) din += sdt[t][r] * wdt[r];
    float dt = softplusf_(din);
    float xc = xcb[(size_t)t * DI];
    float bc = dt * xc;
#pragma unroll
    for (int k = 0; k < DS; k++){
      float a = __expf(dt * eA[k]);
      Pr[k] *= a;
      Fr[k] = Fr[k] * a + bc * sB[t][k];
    }
  }
  size_t base = (((size_t)s * NCHUNK + c) * DI + d) * DS;
#pragma unroll
  for (int k = 0; k < DS; k++){ P[base + k] = Pr[k]; F[base + k] = Fr[k]; }
}

// ---------------- scan pass 2: combine chunk boundaries ----------------
__global__ void k_pass2(const float* __restrict__ P, const float* __restrict__ F, float* __restrict__ Hinit){
  int gi = blockIdx.x * blockDim.x + threadIdx.x;
  if (gi >= NSEQ * DI * DS) return;
  int s = gi / (DI * DS), i = gi % (DI * DS);
  float H = 0.f;
  for (int c = 0; c < NCHUNK; c++){
    size_t o = ((size_t)s * NCHUNK + c) * (DI * DS) + i;
    Hinit[o] = H;
    H = F[o] + P[o] * H;
  }
}

// ---------------- scan pass 3: replay + y scatter ----------------
__global__ __launch_bounds__(384) void k_pass3(
    const float* __restrict__ xc_all, const float* __restrict__ dtin_all,
    const float* __restrict__ B_all, const float* __restrict__ C_all,
    const float* __restrict__ A_log, const float* __restrict__ dtw, const float* __restrict__ dtb,
    const float* __restrict__ Dp, const float* __restrict__ Hinit,
    const int* __restrict__ p1, const int* __restrict__ p2, const int* __restrict__ p3,
    float* __restrict__ ysum){
  int s = blockIdx.y, c = blockIdx.x;
  int d = threadIdx.x;
  int pi = s >> 1, rev = s & 1;
  const int* perm = (pi == 1) ? p1 : (pi == 2) ? p2 : (pi == 3) ? p3 : nullptr;
  __shared__ float sB[CHL][DS];
  __shared__ float sC[CHL][DS];
  __shared__ float sdt[CHL][DTR];
  __shared__ int sorig[CHL];
  int n0 = c * CHL;
  for (int i = d; i < CHL * DS; i += 384){
    sB[i / DS][i % DS] = B_all[((size_t)s * N + n0) * DS + i];
    sC[i / DS][i % DS] = C_all[((size_t)s * N + n0) * DS + i];
  }
  for (int i = d; i < CHL * DTR; i += 384) sdt[i / DTR][i % DTR] = dtin_all[((size_t)s * N + n0) * DTR + i];
  for (int t = d; t < CHL; t += 384){
    int n = n0 + t;
    int pos = rev ? (N - 1 - n) : n;
    sorig[t] = perm ? perm[pos] : pos;
  }
  __syncthreads();
  float eA[DS], wdt[DTR];
#pragma unroll
  for (int k = 0; k < DS; k++) eA[k] = -__expf(A_log[d * DS + k]);
#pragma unroll
  for (int r = 0; r < DTR; r++) wdt[r] = dtw[d * DTR + r];
  float bdt = dtb[d];
  float Dpd = Dp[d];
  float hreg[DS];
  size_t hb = (((size_t)s * NCHUNK + c) * DI + d) * DS;
#pragma unroll
  for (int k = 0; k < DS; k++) hreg[k] = Hinit[hb + k];
  const float* xcb = xc_all + ((size_t)s * N + n0) * DI + d;
  for (int t = 0; t < CHL; t++){
    float din = bdt;
#pragma unroll
    for (int r = 0; r < DTR; r++) din += sdt[t][r] * wdt[r];
    float dt = softplusf_(din);
    float xc = xcb[(size_t)t * DI];
    float bc = dt * xc;
    float y = 0.f;
#pragma unroll
    for (int k = 0; k < DS; k++){
      float a = __expf(dt * eA[k]);
      hreg[k] = hreg[k] * a + bc * sB[t][k];
      y += hreg[k] * sC[t][k];
    }
    y += xc * Dpd;
    atomicAdd(&ysum[(size_t)sorig[t] * DI + d], y * 0.125f);
  }
}

// ---------------- out_proj (fused g = ysum * silu(z)): h2 = g @ out_proj_w^T ----------------
__global__ __launch_bounds__(256) void k_outproj(const float* __restrict__ ysum, const float* __restrict__ z,
     const float* __restrict__ w, float* __restrict__ h2){
  __shared__ float sg[16 * DI];
  int n0 = blockIdx.x * 16, tid = threadIdx.x;
  for (int i = tid; i < 16 * DI / 4; i += 256){
    float4 yv = ((const float4*)(ysum + (size_t)n0*DI))[i];
    float4 zv = ((const float4*)(z + (size_t)n0*DI))[i];
    float4 g;
    g.x = yv.x*siluf(zv.x); g.y = yv.y*siluf(zv.y);
    g.z = yv.z*siluf(zv.z); g.w = yv.w*siluf(zv.w);
    ((float4*)sg)[i] = g;
  }
  __syncthreads();
  int rg = tid >> 6, cg = tid & 63;  // cols cg*3..+2
  float acc[4][3] = {};
  for (int k = 0; k < DI; k += 4){
    float4 xv[4];
#pragma unroll
    for (int m = 0; m < 4; m++) xv[m] = *(const float4*)(sg + (rg*4+m)*DI + k);
#pragma unroll
    for (int c = 0; c < 3; c++){
      float4 wv = *(const float4*)(w + (size_t)(cg*3+c)*DI + k);
#pragma unroll
      for (int m = 0; m < 4; m++)
        acc[m][c] += wv.x*xv[m].x + wv.y*xv[m].y + wv.z*xv[m].z + wv.w*xv[m].w;
    }
  }
#pragma unroll
  for (int m = 0; m < 4; m++)
#pragma unroll
    for (int c = 0; c < 3; c++)
      h2[(size_t)(n0+rg*4+m)*DM + cg*3+c] = acc[m][c];
}

// ---------------- GNN edge kernels ----------------
__global__ void k_edge_max(const int* __restrict__ ei, const float* __restrict__ h2,
                           const float* __restrict__ gt, unsigned* __restrict__ mxe){
  int gi = blockIdx.x * blockDim.x + threadIdx.x;
  if (gi >= E_EDGES * DM) return;
  int e = gi / DM, dd = gi % DM;
  int src = ei[e], dst = ei[E_EDGES + e];
  float m = h2[(size_t)src * DM + dd]; m = (m > 0.f ? m : 0.f) + EPSG;
  float logit = gt[0] * m;
  atomicMax(&mxe[(size_t)dst * DM + dd], fenc(logit));
}

__global__ void k_mxfin(unsigned* __restrict__ mxe){
  int i = blockIdx.x * blockDim.x + threadIdx.x;
  if (i < N * DM){
    float f = fdec(mxe[i]);
    if (!isfinite(f)) f = 0.f;
    ((float*)mxe)[i] = f;
  }
}

__global__ void k_edge_den(const int* __restrict__ ei, const float* __restrict__ h2,
                           const float* __restrict__ gt, const float* __restrict__ mx,
                           float* __restrict__ den){
  int gi = blockIdx.x * blockDim.x + threadIdx.x;
  if (gi >= E_EDGES * DM) return;
  int e = gi / DM, dd = gi % DM;
  int src = ei[e], dst = ei[E_EDGES + e];
  float m = h2[(size_t)src * DM + dd]; m = (m > 0.f ? m : 0.f) + EPSG;
  float ex = __expf(gt[0] * m - mx[(size_t)dst * DM + dd]);
  atomicAdd(&den[(size_t)dst * DM + dd], ex);
}

__global__ void k_edge_aggr(const int* __restrict__ ei, const float* __restrict__ h2,
                            const float* __restrict__ gt, const float* __restrict__ mx,
                            const float* __restrict__ den, float* __restrict__ aggr){
  int gi = blockIdx.x * blockDim.x + threadIdx.x;
  if (gi >= E_EDGES * DM) return;
  int e = gi / DM, dd = gi % DM;
  int src = ei[e], dst = ei[E_EDGES + e];
  float m = h2[(size_t)src * DM + dd]; m = (m > 0.f ? m : 0.f) + EPSG;
  float ex = __expf(gt[0] * m - mx[(size_t)dst * DM + dd]);
  float dn = den[(size_t)dst * DM + dd];
  float alpha = ex / (dn > 0.f ? dn : 1.f);
  atomicAdd(&aggr[(size_t)dst * DM + dd], alpha * m);
}

// ---------------- mlp1: u2 = relu(LN((aggr+h2) @ mlp1^T + b)) ----------------
__global__ __launch_bounds__(256) void k_mlp1(const float* __restrict__ aggr, const float* __restrict__ h2,
    const float* __restrict__ w, const float* __restrict__ b,
    const float* __restrict__ lg, const float* __restrict__ lb, float* __restrict__ u2){
  __shared__ float su[16 * DM];
  __shared__ float uu[16][2*DM];
  __shared__ float sm[16], sr[16];
  int n0 = blockIdx.x * 16, tid = threadIdx.x;
  for (int i = tid; i < 16 * DM / 4; i += 256){
    float4 a = ((const float4*)(aggr + (size_t)n0*DM))[i];
    float4 hh = ((const float4*)(h2 + (size_t)n0*DM))[i];
    float4 r; r.x=a.x+hh.x; r.y=a.y+hh.y; r.z=a.z+hh.z; r.w=a.w+hh.w;
    ((float4*)su)[i] = r;
  }
  __syncthreads();
  int rg = tid >> 6, cg = tid & 63, lane = tid & 63;  // cols cg*6..+5
  float acc[4][6] = {};
  for (int k = 0; k < DM; k += 4){
    float4 xv[4];
#pragma unroll
    for (int m = 0; m < 4; m++) xv[m] = *(const float4*)(su + (rg*4+m)*DM + k);
#pragma unroll
    for (int c = 0; c < 6; c++){
      float4 wv = *(const float4*)(w + (size_t)(cg*6+c)*DM + k);
#pragma unroll
      for (int m = 0; m < 4; m++)
        acc[m][c] += wv.x*xv[m].x + wv.y*xv[m].y + wv.z*xv[m].z + wv.w*xv[m].w;
    }
  }
#pragma unroll
  for (int c = 0; c < 6; c++){
    float bb = b[cg*6+c];
#pragma unroll
    for (int m = 0; m < 4; m++) uu[rg*4+m][cg*6+c] = acc[m][c] + bb;
  }
  __syncthreads();
#pragma unroll
  for (int q = 0; q < 4; q++){
    int r = rg*4 + q;
    float s1 = 0.f, s2 = 0.f;
#pragma unroll
    for (int t = 0; t < 6; t++){ float v = uu[r][t*64+lane]; s1 += v; s2 += v*v; }
#pragma unroll
    for (int o = 32; o > 0; o >>= 1){ s1 += __shfl_xor(s1,o); s2 += __shfl_xor(s2,o); }
    if (lane == 0){ float mean = s1/384.f; sm[r] = mean; sr[r] = rsqrtf(s2/384.f - mean*mean + LN_EPS); }
  }
  __syncthreads();
  for (int i = tid; i < 16*2*DM; i += 256){
    int r = i/(2*DM), c = i%(2*DM);
    float v = (uu[r][c]-sm[r])*sr[r]*lg[c]+lb[c];
    u2[(size_t)(n0+r)*DI + c] = v > 0.f ? v : 0.f;
  }
}

// ---------------- mlp2 + LN + residuals + final LN + attention score, fused ----------------
__global__ __launch_bounds__(256) void k_mlp2attn(const float* __restrict__ u2, const float* __restrict__ w,
    const float* __restrict__ b, const float* __restrict__ gg, const float* __restrict__ gb,
    const float* __restrict__ h2, const float* __restrict__ hres,
    const float* __restrict__ ng, const float* __restrict__ nb,
    const float* __restrict__ w1, const float* __restrict__ b1,
    const float* __restrict__ w2, const float* __restrict__ b2,
    float* __restrict__ hn2, float* __restrict__ ascore){
  __shared__ float su[16 * DI];
  __shared__ float go[16][DM];
  __shared__ float sm[16], sr[16];
  int n0 = blockIdx.x * 16, tid = threadIdx.x;
  for (int i = tid; i < 16 * DI / 4; i += 256)
    ((float4*)su)[i] = ((const float4*)(u2 + (size_t)n0*DI))[i];
  __syncthreads();
  int rg = tid >> 6, cg = tid & 63, lane = tid & 63;
  float acc[4][3] = {};
  for (int k = 0; k < DI; k += 4){
    float4 xv[4];
#pragma unroll
    for (int m = 0; m < 4; m++) xv[m] = *(const float4*)(su + (rg*4+m)*DI + k);
#pragma unroll
    for (int c = 0; c < 3; c++){
      float4 wv = *(const float4*)(w + (size_t)(cg*3+c)*DI + k);
#pragma unroll
      for (int m = 0; m < 4; m++)
        acc[m][c] += wv.x*xv[m].x + wv.y*xv[m].y + wv.z*xv[m].z + wv.w*xv[m].w;
    }
  }
#pragma unroll
  for (int c = 0; c < 3; c++){
    float bb = b[cg*3+c];
#pragma unroll
    for (int m = 0; m < 4; m++) go[rg*4+m][cg*3+c] = acc[m][c] + bb;
  }
  __syncthreads();
  // LN(gout) stats
#pragma unroll
  for (int q = 0; q < 4; q++){
    int r = rg*4 + q;
    float v0 = go[r][lane], v1 = go[r][64+lane], v2 = go[r][128+lane];
    float s1 = v0+v1+v2, s2 = v0*v0+v1*v1+v2*v2;
#pragma unroll
    for (int o = 32; o > 0; o >>= 1){ s1 += __shfl_xor(s1,o); s2 += __shfl_xor(s2,o); }
    if (lane == 0){ float mean = s1/192.f; sm[r] = mean; sr[r] = rsqrtf(s2/192.f - mean*mean + LN_EPS); }
  }
  __syncthreads();
  // h4 = h2 + relu(LN(gout)) + hres  (in place in go)
  for (int i = tid; i < 16*DM; i += 256){
    int r = i/DM, c = i%DM;
    float v = (go[r][c]-sm[r])*sr[r]*gg[c]+gb[c];
    v = v > 0.f ? v : 0.f;
    int n = n0 + r;
    go[r][c] = h2[(size_t)n*DM + c] + v + hres[(size_t)n*DM + c];
  }
  __syncthreads();
  // final LN stats
#pragma unroll
  for (int q = 0; q < 4; q++){
    int r = rg*4 + q;
    float v0 = go[r][lane], v1 = go[r][64+lane], v2 = go[r][128+lane];
    float s1 = v0+v1+v2, s2 = v0*v0+v1*v1+v2*v2;
#pragma unroll
    for (int o = 32; o > 0; o >>= 1){ s1 += __shfl_xor(s1,o); s2 += __shfl_xor(s2,o); }
    if (lane == 0){ float mean = s1/192.f; sm[r] = mean; sr[r] = rsqrtf(s2/192.f - mean*mean + LN_EPS); }
  }
  __syncthreads();
  float* sh = su;   // reuse as hn2 tile [16][192]
  for (int i = tid; i < 16*DM; i += 256){
    int r = i/DM, c = i%DM;
    float v = (go[r][c]-sm[r])*sr[r]*ng[c]+nb[c];
    hn2[(size_t)(n0+r)*DM + c] = v;
    sh[r*DM + c] = v;
  }
  __syncthreads();
  // attention score: wave rg handles rows rg*4..+3; lane covers hidden cols lane, lane+64
#pragma unroll
  for (int q = 0; q < 4; q++){
    int r = rg*4 + q;
    float a0 = b1[lane], a1 = b1[64+lane];
    for (int k = 0; k < DM; k += 4){
      float4 hv = *(const float4*)(sh + r*DM + k);
      float4 wa = *(const float4*)(w1 + (size_t)lane*DM + k);
      float4 wb = *(const float4*)(w1 + (size_t)(64+lane)*DM + k);
      a0 += wa.x*hv.x + wa.y*hv.y + wa.z*hv.z + wa.w*hv.w;
      a1 += wb.x*hv.x + wb.y*hv.y + wb.z*hv.z + wb.w*hv.w;
    }
    float t = tanhf(a0)*w2[lane] + tanhf(a1)*w2[64+lane];
#pragma unroll
    for (int o = 32; o > 0; o >>= 1) t += __shfl_xor(t, o);
    if (lane == 0) ascore[r + n0] = t + b2[0];
  }
}

// ---------------- softmax over a[N] (in place -> weights) ----------------
__global__ __launch_bounds__(1024) void k_softmax(float* __restrict__ a){
  int tid = threadIdx.x;
  __shared__ float rb[16];
  float mx = -1e30f;
  for (int i = tid; i < N; i += 1024) mx = fmaxf(mx, a[i]);
#pragma unroll
  for (int o = 32; o > 0; o >>= 1) mx = fmaxf(mx, __shfl_down(mx, o));
  if ((tid & 63) == 0) rb[tid >> 6] = mx;
  __syncthreads();
  float m = -1e30f;
  for (int i = 0; i < 16; i++) m = fmaxf(m, rb[i]);
  __syncthreads();
  float z = 0.f;
  for (int i = tid; i < N; i += 1024) z += __expf(a[i] - m);
#pragma unroll
  for (int o = 32; o > 0; o >>= 1) z += __shfl_down(z, o);
  if ((tid & 63) == 0) rb[tid >> 6] = z;
  __syncthreads();
  float Z = 0.f;
  for (int i = 0; i < 16; i++) Z += rb[i];
  float inv = 1.f / Z;
  for (int i = tid; i < N; i += 1024) a[i] = __expf(a[i] - m) * inv;
}

// ---------------- weighted pool ----------------
__global__ __launch_bounds__(192) void k_pool(const float* __restrict__ wgt, const float* __restrict__ hn2,
                                              float* __restrict__ pooled){
  int bidx = blockIdx.x, d = threadIdx.x;
  float acc = 0.f;
  for (int r = 0; r < 128; r++){
    int n = bidx * 128 + r;
    acc += wgt[n] * hn2[(size_t)n * DM + d];
  }
  atomicAdd(&pooled[d], acc);
}

// ---------------- head ----------------
__global__ __launch_bounds__(64) void k_head(const float* __restrict__ pooled, const float* __restrict__ hw,
                                             const float* __restrict__ hb, float* __restrict__ out){
  int tid = threadIdx.x;
  for (int c = 0; c < 2; c++){
    float s = 0.f;
    for (int d = tid; d < DM; d += 64) s += pooled[d] * hw[c * DM + d];
#pragma unroll
    for (int o = 32; o > 0; o >>= 1) s += __shfl_down(s, o);
    if (tid == 0) out[c] = s + hb[c];
  }
}

extern "C" void kernel_launch(void* const* d_in, const int* in_sizes, int n_in,
                              void* d_out, int out_size, void* d_ws, size_t ws_size,
                              hipStream_t stream){
  (void)in_sizes; (void)n_in; (void)out_size; (void)ws_size;
  const float* x        = (const float*)d_in[0];
  const int*   ei       = (const int*)d_in[1];
  const int*   perm_pre = (const int*)d_in[2];
  const int*   perm_post= (const int*)d_in[3];
  const int*   perm_lvl = (const int*)d_in[4];
  const float* ft_w     = (const float*)d_in[5];
  const float* ft_b     = (const float*)d_in[6];
  const float* ln1_g    = (const float*)d_in[7];
  const float* ln1_b    = (const float*)d_in[8];
  const float* in_proj_w= (const float*)d_in[9];
  const float* conv_w   = (const float*)d_in[10];
  const float* conv_b   = (const float*)d_in[11];
  const float* x_proj_w = (const float*)d_in[12];
  const float* dt_proj_w= (const float*)d_in[13];
  const float* dt_proj_b= (const float*)d_in[14];
  const float* A_log    = (const float*)d_in[15];
  const float* D_param  = (const float*)d_in[16];
  const float* out_proj_w=(const float*)d_in[17];
  const float* gnn_t    = (const float*)d_in[18];
  const float* mlp1_w   = (const float*)d_in[19];
  const float* mlp1_b   = (const float*)d_in[20];
  const float* mlp_ln_g = (const float*)d_in[21];
  const float* mlp_ln_b = (const float*)d_in[22];
  const float* mlp2_w   = (const float*)d_in[23];
  const float* mlp2_b   = (const float*)d_in[24];
  const float* gnn_g    = (const float*)d_in[25];
  const float* gnn_b    = (const float*)d_in[26];
  const float* norm_g   = (const float*)d_in[27];
  const float* norm_b   = (const float*)d_in[28];
  const float* attn1_w  = (const float*)d_in[29];
  const float* attn1_b  = (const float*)d_in[30];
  const float* attn2_w  = (const float*)d_in[31];
  const float* attn2_b  = (const float*)d_in[32];
  const float* head_w   = (const float*)d_in[33];
  const float* head_b   = (const float*)d_in[34];

  float* ws = (float*)d_ws;
  size_t off = 0;
  float* h      = ws + off; off += (size_t)N * DM;
  float* hn     = ws + off; off += (size_t)N * DM;
  float* xi     = ws + off; off += (size_t)N * DI;
  float* z      = ws + off; off += (size_t)N * DI;
  float* xc_all = ws + off; off += (size_t)NSEQ * N * DI;
  float* dtin   = ws + off; off += (size_t)NSEQ * N * DTR;
  float* Ball   = ws + off; off += (size_t)NSEQ * N * DS;
  float* Call   = ws + off; off += (size_t)NSEQ * N * DS;
  float* Pb     = ws + off; off += (size_t)NSEQ * NCHUNK * DI * DS;
  float* Fb     = ws + off; off += (size_t)NSEQ * NCHUNK * DI * DS;
  float* Hin    = ws + off; off += (size_t)NSEQ * NCHUNK * DI * DS;
  float* ysum   = ws + off; off += (size_t)N * DI;
  float* h2     = ws + off; off += (size_t)N * DM;
  float* mx     = ws + off; off += (size_t)N * DM;
  float* den    = ws + off; off += (size_t)N * DM;
  float* aggr   = ws + off; off += (size_t)N * DM;
  float* u2     = ws + off; off += (size_t)N * DI;
  float* hn2    = ws + off; off += (size_t)N * DM;
  float* ascore = ws + off; off += (size_t)N;
  float* pooled = ws + off; off += DM;

  k_init<<<dim3((N * DI + 255) / 256), dim3(256), 0, stream>>>(ysum, (unsigned*)mx, den, aggr, pooled);
  k_ft<<<dim3(N / 16), dim3(256), 0, stream>>>(x, ft_w, ft_b, ln1_g, ln1_b, h, hn);
  k_inproj<<<dim3(N / 16), dim3(256), 0, stream>>>(hn, in_proj_w, xi, z);
  k_stagea<<<dim3(N / 64, NSEQ), dim3(512), 0, stream>>>(xi, perm_pre, perm_post, perm_lvl,
      conv_w, conv_b, x_proj_w, xc_all, dtin, Ball, Call);
  k_pass1<<<dim3(NCHUNK, NSEQ), dim3(384), 0, stream>>>(xc_all, dtin, Ball, A_log, dt_proj_w, dt_proj_b, Pb, Fb);
  k_pass2<<<dim3((NSEQ * DI * DS + 255) / 256), dim3(256), 0, stream>>>(Pb, Fb, Hin);
  k_pass3<<<dim3(NCHUNK, NSEQ), dim3(384), 0, stream>>>(xc_all, dtin, Ball, Call, A_log, dt_proj_w, dt_proj_b,
      D_param, Hin, perm_pre, perm_post, perm_lvl, ysum);
  k_outproj<<<dim3(N / 16), dim3(256), 0, stream>>>(ysum, z, out_proj_w, h2);
  k_edge_max<<<dim3((E_EDGES * DM + 255) / 256), dim3(256), 0, stream>>>(ei, h2, gnn_t, (unsigned*)mx);
  k_mxfin<<<dim3((N * DM + 255) / 256), dim3(256), 0, stream>>>((unsigned*)mx);
  k_edge_den<<<dim3((E_EDGES * DM + 255) / 256), dim3(256), 0, stream>>>(ei, h2, gnn_t, mx, den);
  k_edge_aggr<<<dim3((E_EDGES * DM + 255) / 256), dim3(256), 0, stream>>>(ei, h2, gnn_t, mx, den, aggr);
  k_mlp1<<<dim3(N / 16), dim3(256), 0, stream>>>(aggr, h2, mlp1_w, mlp1_b, mlp_ln_g, mlp_ln_b, u2);
  k_mlp2attn<<<dim3(N / 16), dim3(256), 0, stream>>>(u2, mlp2_w, mlp2_b, gnn_g, gnn_b, h2, h,
      norm_g, norm_b, attn1_w, attn1_b, attn2_w, attn2_b, hn2, ascore);
  k_softmax<<<dim3(1), dim3(1024), 0, stream>>>(ascore);
  k_pool<<<dim3(N / 128), dim3(192), 0, stream>>>(ascore, hn2, pooled);
  k_head<<<dim3(1), dim3(64), 0, stream>>>(pooled, head_w, head_b, (float*)d_out);
}

// Round 3
// 802.740 us; speedup vs baseline: 1.3806x; 1.1143x over previous
//
#include <hip/hip_runtime.h>
#include <hip/hip_bf16.h>
#include <math.h>

#define N 4096
#define E_EDGES 32768
#define IN_DIM 1024
#define DM 192
#define DI 384
#define DS 16
#define DC 4
#define DTR 12
#define NSEQ 8
#define NCHUNK 64
#define CHL (N / NCHUNK)   /* 64 */
#define EPSG 1e-7f
#define LN_EPS 1e-5f

__device__ __forceinline__ float siluf(float x){ return x / (1.f + __expf(-x)); }
__device__ __forceinline__ float softplusf_(float x){ return (x > 20.f) ? x : log1pf(__expf(x)); }

// Multi-value fold: input p[8] = partials for rows 0..7 (each lane has its own
// 6-d slice summed). Output: full 64-lane sum for row R(lane) where
// R = 4*bit0(lane) + 2*bit1(lane) + bit2(lane). 10 shuffles total.
__device__ __forceinline__ float fold8(const float p[8], int lane){
  float q[4];
#pragma unroll
  for (int k = 0; k < 4; k++){
    float send = (lane & 1) ? p[k] : p[k+4];
    float recv = __shfl_xor(send, 1);
    q[k] = ((lane & 1) ? p[k+4] : p[k]) + recv;
  }
  float r2[2];
#pragma unroll
  for (int k = 0; k < 2; k++){
    float send = (lane & 2) ? q[k] : q[k+2];
    float recv = __shfl_xor(send, 2);
    r2[k] = ((lane & 2) ? q[k+2] : q[k]) + recv;
  }
  float s;
  {
    float send = (lane & 4) ? r2[0] : r2[1];
    float recv = __shfl_xor(send, 4);
    s = ((lane & 4) ? r2[1] : r2[0]) + recv;
  }
  s += __shfl_xor(s, 8);
  s += __shfl_xor(s, 16);
  s += __shfl_xor(s, 32);
  return s;
}

// ---------------- init ----------------
__global__ void k_init(float* __restrict__ ysum, float* __restrict__ den,
                       float* __restrict__ aggrn, float* __restrict__ pooled){
  int i = blockIdx.x * blockDim.x + threadIdx.x;
  if (i < N * DI) ysum[i] = 0.f;
  if (i < N * DM){ den[i] = 0.f; aggrn[i] = 0.f; }
  if (i < DM) pooled[i] = 0.f;
}

// ---------------- feature transform + LN1 fused ----------------
__global__ __launch_bounds__(256) void k_ft(const float* __restrict__ x, const float* __restrict__ w,
     const float* __restrict__ b, const float* __restrict__ lg, const float* __restrict__ lb,
     float* __restrict__ h, float* __restrict__ hn){
  __shared__ float xs[16 * IN_DIM];
  __shared__ float hs[16][DM];
  __shared__ float sm[16], sr[16];
  int n0 = blockIdx.x * 16, tid = threadIdx.x;
  { const float4* src = (const float4*)(x + (size_t)n0 * IN_DIM);
    float4* dst = (float4*)xs;
    for (int i = tid; i < 16 * IN_DIM / 4; i += 256) dst[i] = src[i]; }
  __syncthreads();
  int rg = tid >> 6;
  int cg = tid & 63;
  float acc[4][3] = {};
  for (int k = 0; k < IN_DIM; k += 4){
    float4 xv[4];
#pragma unroll
    for (int m = 0; m < 4; m++) xv[m] = *(const float4*)(xs + (rg*4+m)*IN_DIM + k);
#pragma unroll
    for (int c = 0; c < 3; c++){
      float4 wv = *(const float4*)(w + (size_t)(cg*3+c)*IN_DIM + k);
#pragma unroll
      for (int m = 0; m < 4; m++)
        acc[m][c] += wv.x*xv[m].x + wv.y*xv[m].y + wv.z*xv[m].z + wv.w*xv[m].w;
    }
  }
#pragma unroll
  for (int c = 0; c < 3; c++){
    float bb = b[cg*3+c];
#pragma unroll
    for (int m = 0; m < 4; m++){
      float v = acc[m][c] + bb; v = v > 0.f ? v : 0.f;
      hs[rg*4+m][cg*3+c] = v;
      h[(size_t)(n0+rg*4+m)*DM + cg*3+c] = v;
    }
  }
  __syncthreads();
  int lane = tid & 63;
#pragma unroll
  for (int q = 0; q < 4; q++){
    int r = rg*4 + q;
    float v0 = hs[r][lane], v1 = hs[r][64+lane], v2 = hs[r][128+lane];
    float s1 = v0+v1+v2, s2 = v0*v0+v1*v1+v2*v2;
#pragma unroll
    for (int o = 32; o > 0; o >>= 1){ s1 += __shfl_xor(s1,o); s2 += __shfl_xor(s2,o); }
    if (lane == 0){ float mean = s1/192.f; sm[r] = mean; sr[r] = rsqrtf(s2/192.f - mean*mean + LN_EPS); }
  }
  __syncthreads();
  for (int i = tid; i < 16*DM; i += 256){
    int r = i/DM, c = i%DM;
    hn[(size_t)(n0+r)*DM + c] = (hs[r][c]-sm[r])*sr[r]*lg[c] + lb[c];
  }
}

// ---------------- in_proj ----------------
__global__ __launch_bounds__(256) void k_inproj(const float* __restrict__ hn, const float* __restrict__ w,
                                                float* __restrict__ xi, float* __restrict__ z){
  __shared__ float s[16 * DM];
  int n0 = blockIdx.x * 16, tid = threadIdx.x;
  { const float4* src = (const float4*)(hn + (size_t)n0 * DM);
    float4* dst = (float4*)s;
    for (int i = tid; i < 16 * DM / 4; i += 256) dst[i] = src[i]; }
  __syncthreads();
  int rg = tid >> 6, cg = tid & 63;
  float acc[4][12] = {};
  for (int k = 0; k < DM; k += 4){
    float4 xv[4];
#pragma unroll
    for (int m = 0; m < 4; m++) xv[m] = *(const float4*)(s + (rg*4+m)*DM + k);
#pragma unroll
    for (int c = 0; c < 12; c++){
      float4 wv = *(const float4*)(w + (size_t)(cg*12+c)*DM + k);
#pragma unroll
      for (int m = 0; m < 4; m++)
        acc[m][c] += wv.x*xv[m].x + wv.y*xv[m].y + wv.z*xv[m].z + wv.w*xv[m].w;
    }
  }
#pragma unroll
  for (int m = 0; m < 4; m++){
    int n = n0 + rg*4 + m;
#pragma unroll
    for (int c = 0; c < 12; c++){
      int j = cg*12 + c;
      if (j < DI) xi[(size_t)n*DI + j] = acc[m][c];
      else        z [(size_t)n*DI + (j-DI)] = acc[m][c];
    }
  }
}

// ---------------- stage A: gather + conv + silu + x_proj (fold-tree reduce) ----------------
__global__ __launch_bounds__(512) void k_stagea(const float* __restrict__ xi,
    const int* __restrict__ p1, const int* __restrict__ p2, const int* __restrict__ p3,
    const float* __restrict__ conv_w, const float* __restrict__ conv_b,
    const float* __restrict__ xpw,
    float* __restrict__ xc_all, float* __restrict__ dtin_all,
    float* __restrict__ B_all, float* __restrict__ C_all){
  __shared__ float sW[44 * DI];
  __shared__ float sOut[8][8][46];   // [wave][row][j] (padded)
  int s = blockIdx.y;
  int tid = threadIdx.x;
  { const float4* src = (const float4*)xpw;
    float4* dst = (float4*)sW;
    for (int i = tid; i < 44 * DI / 4; i += 512) dst[i] = src[i]; }
  int wid = tid >> 6, lane = tid & 63;
  int pi = s >> 1, rev = s & 1;
  const int* perm = (pi == 1) ? p1 : (pi == 2) ? p2 : (pi == 3) ? p3 : nullptr;
  int nbase = blockIdx.x * 64 + wid * 8;
  float4 cw[6]; float cb[6];
#pragma unroll
  for (int r = 0; r < 6; r++){
    int d = r*64 + lane;
    cw[r] = *(const float4*)(conv_w + d*DC);
    cb[r] = conv_b[d];
  }
  __syncthreads();
  // rolling 4-tap window of gathered xi rows (lane owns d = r*64+lane)
  float tap[4][6];
#pragma unroll
  for (int t = 0; t < 4; t++){
    int nn = nbase - 3 + t;
    if (nn >= 0){
      int pos = rev ? (N-1-nn) : nn;
      int srcr = perm ? perm[pos] : pos;
      const float* xr = xi + (size_t)srcr * DI;
#pragma unroll
      for (int r = 0; r < 6; r++) tap[t][r] = xr[r*64 + lane];
    } else {
#pragma unroll
      for (int r = 0; r < 6; r++) tap[t][r] = 0.f;
    }
  }
  float xv[8][6];
#pragma unroll
  for (int i = 0; i < 8; i++){
    int n = nbase + i;
#pragma unroll
    for (int r = 0; r < 6; r++){
      float a = cb[r] + tap[0][r]*cw[r].x + tap[1][r]*cw[r].y + tap[2][r]*cw[r].z + tap[3][r]*cw[r].w;
      xv[i][r] = siluf(a);
    }
    float* xo = xc_all + ((size_t)s*N + n)*DI;
#pragma unroll
    for (int r = 0; r < 6; r++) xo[r*64 + lane] = xv[i][r];
    if (i < 7){
#pragma unroll
      for (int t = 0; t < 3; t++)
#pragma unroll
        for (int r = 0; r < 6; r++) tap[t][r] = tap[t+1][r];
      int nn = n + 1;
      int pos = rev ? (N-1-nn) : nn;
      int srcr = perm ? perm[pos] : pos;
      const float* xr = xi + (size_t)srcr * DI;
#pragma unroll
      for (int r = 0; r < 6; r++) tap[3][r] = xr[r*64 + lane];
    }
  }
  // x_proj: per j, partials for 8 rows over this lane's 6 d's, then 10-shfl fold.
  int R = 4*(lane & 1) + 2*((lane >> 1) & 1) + ((lane >> 2) & 1);
  for (int j = 0; j < 44; j++){
    const float* wj = sW + j*DI;
    float w0 = wj[lane],      w1 = wj[64+lane],  w2 = wj[128+lane];
    float w3 = wj[192+lane],  w4 = wj[256+lane], w5 = wj[320+lane];
    float p[8];
#pragma unroll
    for (int i = 0; i < 8; i++)
      p[i] = xv[i][0]*w0 + xv[i][1]*w1 + xv[i][2]*w2
           + xv[i][3]*w3 + xv[i][4]*w4 + xv[i][5]*w5;
    float red = fold8(p, lane);
    if (lane < 8) sOut[wid][R][j] = red;
  }
  __syncthreads();
#pragma unroll
  for (int i = 0; i < 8; i++){
    float v = sOut[wid][i][lane < 44 ? lane : 0];
    size_t base = (size_t)s*N + (nbase + i);
    if (lane < DTR)              dtin_all[base*DTR + lane] = v;
    else if (lane < DTR+DS)      B_all[base*DS + (lane-DTR)] = v;
    else if (lane < DTR+2*DS)    C_all[base*DS + (lane-DTR-DS)] = v;
  }
}

// ---------------- scan pass 1 ----------------
__global__ __launch_bounds__(384) void k_pass1(
    const float* __restrict__ xc_all, const float* __restrict__ dtin_all,
    const float* __restrict__ B_all, const float* __restrict__ A_log,
    const float* __restrict__ dtw, const float* __restrict__ dtb,
    float* __restrict__ P, float* __restrict__ F){
  int s = blockIdx.y, c = blockIdx.x;
  int d = threadIdx.x;
  __shared__ float sB[CHL][DS];
  __shared__ float sdt[CHL][DTR];
  int n0 = c * CHL;
  for (int i = d; i < CHL * DS; i += 384) sB[i / DS][i % DS] = B_all[((size_t)s * N + n0) * DS + i];
  for (int i = d; i < CHL * DTR; i += 384) sdt[i / DTR][i % DTR] = dtin_all[((size_t)s * N + n0) * DTR + i];
  __syncthreads();
  float eA[DS], wdt[DTR];
#pragma unroll
  for (int k = 0; k < DS; k++) eA[k] = -__expf(A_log[d * DS + k]);
#pragma unroll
  for (int r = 0; r < DTR; r++) wdt[r] = dtw[d * DTR + r];
  float bdt = dtb[d];
  float Pr[DS], Fr[DS];
#pragma unroll
  for (int k = 0; k < DS; k++){ Pr[k] = 1.f; Fr[k] = 0.f; }
  const float* xcb = xc_all + ((size_t)s * N + n0) * DI + d;
  for (int t = 0; t < CHL; t++){
    float din = bdt;
#pragma unroll
    for (int r = 0; r < DTR; r++) din += sdt[t][r] * wdt[r];
    float dt = softplusf_(din);
    float xc = xcb[(size_t)t * DI];
    float bc = dt * xc;
#pragma unroll
    for (int k = 0; k < DS; k++){
      float a = __expf(dt * eA[k]);
      Pr[k] *= a;
      Fr[k] = Fr[k] * a + bc * sB[t][k];
    }
  }
  size_t base = (((size_t)s * NCHUNK + c) * DI + d) * DS;
#pragma unroll
  for (int k = 0; k < DS; k++){ P[base + k] = Pr[k]; F[base + k] = Fr[k]; }
}

// ---------------- scan pass 2 ----------------
__global__ void k_pass2(const float* __restrict__ P, const float* __restrict__ F, float* __restrict__ Hinit){
  int gi = blockIdx.x * blockDim.x + threadIdx.x;
  if (gi >= NSEQ * DI * DS) return;
  int s = gi / (DI * DS), i = gi % (DI * DS);
  float H = 0.f;
  for (int c = 0; c < NCHUNK; c++){
    size_t o = ((size_t)s * NCHUNK + c) * (DI * DS) + i;
    Hinit[o] = H;
    H = F[o] + P[o] * H;
  }
}

// ---------------- scan pass 3: replay + y scatter ----------------
__global__ __launch_bounds__(384) void k_pass3(
    const float* __restrict__ xc_all, const float* __restrict__ dtin_all,
    const float* __restrict__ B_all, const float* __restrict__ C_all,
    const float* __restrict__ A_log, const float* __restrict__ dtw, const float* __restrict__ dtb,
    const float* __restrict__ Dp, const float* __restrict__ Hinit,
    const int* __restrict__ p1, const int* __restrict__ p2, const int* __restrict__ p3,
    float* __restrict__ ysum){
  int s = blockIdx.y, c = blockIdx.x;
  int d = threadIdx.x;
  int pi = s >> 1, rev = s & 1;
  const int* perm = (pi == 1) ? p1 : (pi == 2) ? p2 : (pi == 3) ? p3 : nullptr;
  __shared__ float sB[CHL][DS];
  __shared__ float sC[CHL][DS];
  __shared__ float sdt[CHL][DTR];
  __shared__ int sorig[CHL];
  int n0 = c * CHL;
  for (int i = d; i < CHL * DS; i += 384){
    sB[i / DS][i % DS] = B_all[((size_t)s * N + n0) * DS + i];
    sC[i / DS][i % DS] = C_all[((size_t)s * N + n0) * DS + i];
  }
  for (int i = d; i < CHL * DTR; i += 384) sdt[i / DTR][i % DTR] = dtin_all[((size_t)s * N + n0) * DTR + i];
  for (int t = d; t < CHL; t += 384){
    int n = n0 + t;
    int pos = rev ? (N - 1 - n) : n;
    sorig[t] = perm ? perm[pos] : pos;
  }
  __syncthreads();
  float eA[DS], wdt[DTR];
#pragma unroll
  for (int k = 0; k < DS; k++) eA[k] = -__expf(A_log[d * DS + k]);
#pragma unroll
  for (int r = 0; r < DTR; r++) wdt[r] = dtw[d * DTR + r];
  float bdt = dtb[d];
  float Dpd = Dp[d];
  float hreg[DS];
  size_t hb = (((size_t)s * NCHUNK + c) * DI + d) * DS;
#pragma unroll
  for (int k = 0; k < DS; k++) hreg[k] = Hinit[hb + k];
  const float* xcb = xc_all + ((size_t)s * N + n0) * DI + d;
  for (int t = 0; t < CHL; t++){
    float din = bdt;
#pragma unroll
    for (int r = 0; r < DTR; r++) din += sdt[t][r] * wdt[r];
    float dt = softplusf_(din);
    float xc = xcb[(size_t)t * DI];
    float bc = dt * xc;
    float y = 0.f;
#pragma unroll
    for (int k = 0; k < DS; k++){
      float a = __expf(dt * eA[k]);
      hreg[k] = hreg[k] * a + bc * sB[t][k];
      y += hreg[k] * sC[t][k];
    }
    y += xc * Dpd;
    atomicAdd(&ysum[(size_t)sorig[t] * DI + d], y * 0.125f);
  }
}

// ---------------- out_proj (fused g = ysum * silu(z)) ----------------
__global__ __launch_bounds__(256) void k_outproj(const float* __restrict__ ysum, const float* __restrict__ z,
     const float* __restrict__ w, float* __restrict__ h2){
  __shared__ float sg[16 * DI];
  int n0 = blockIdx.x * 16, tid = threadIdx.x;
  for (int i = tid; i < 16 * DI / 4; i += 256){
    float4 yv = ((const float4*)(ysum + (size_t)n0*DI))[i];
    float4 zv = ((const float4*)(z + (size_t)n0*DI))[i];
    float4 g;
    g.x = yv.x*siluf(zv.x); g.y = yv.y*siluf(zv.y);
    g.z = yv.z*siluf(zv.z); g.w = yv.w*siluf(zv.w);
    ((float4*)sg)[i] = g;
  }
  __syncthreads();
  int rg = tid >> 6, cg = tid & 63;
  float acc[4][3] = {};
  for (int k = 0; k < DI; k += 4){
    float4 xv[4];
#pragma unroll
    for (int m = 0; m < 4; m++) xv[m] = *(const float4*)(sg + (rg*4+m)*DI + k);
#pragma unroll
    for (int c = 0; c < 3; c++){
      float4 wv = *(const float4*)(w + (size_t)(cg*3+c)*DI + k);
#pragma unroll
      for (int m = 0; m < 4; m++)
        acc[m][c] += wv.x*xv[m].x + wv.y*xv[m].y + wv.z*xv[m].z + wv.w*xv[m].w;
    }
  }
#pragma unroll
  for (int m = 0; m < 4; m++)
#pragma unroll
    for (int c = 0; c < 3; c++)
      h2[(size_t)(n0+rg*4+m)*DM + cg*3+c] = acc[m][c];
}

// ---------------- fused GNN edge kernel: den += e^logit ; aggrn += e^logit * msg ----------------
// softmax is shift-invariant; logits = t*(relu(h2)+eps) are bounded (clamp 80 for safety),
// so the segment-max pass is unnecessary: alpha*msg summed == (sum ex*msg)/(sum ex).
__global__ void k_edge(const int* __restrict__ ei, const float* __restrict__ h2,
                       const float* __restrict__ gt,
                       float* __restrict__ den, float* __restrict__ aggrn){
  int gi = blockIdx.x * blockDim.x + threadIdx.x;
  if (gi >= E_EDGES * DM) return;
  int e = gi / DM, dd = gi % DM;
  int src = ei[e], dst = ei[E_EDGES + e];
  float m = h2[(size_t)src * DM + dd]; m = (m > 0.f ? m : 0.f) + EPSG;
  float logit = gt[0] * m;
  float ex = __expf(fminf(logit, 80.f));
  atomicAdd(&den[(size_t)dst * DM + dd], ex);
  atomicAdd(&aggrn[(size_t)dst * DM + dd], ex * m);
}

// ---------------- mlp1: u2 = relu(LN((aggrn/den + h2) @ mlp1^T + b)) ----------------
__global__ __launch_bounds__(256) void k_mlp1(const float* __restrict__ aggrn, const float* __restrict__ den,
    const float* __restrict__ h2,
    const float* __restrict__ w, const float* __restrict__ b,
    const float* __restrict__ lg, const float* __restrict__ lb, float* __restrict__ u2){
  __shared__ float su[16 * DM];
  __shared__ float uu[16][2*DM];
  __shared__ float sm[16], sr[16];
  int n0 = blockIdx.x * 16, tid = threadIdx.x;
  for (int i = tid; i < 16 * DM; i += 256){
    float dn = den[(size_t)n0*DM + i];
    float an = aggrn[(size_t)n0*DM + i];
    float ag = dn > 0.f ? an / dn : 0.f;
    su[i] = ag + h2[(size_t)n0*DM + i];
  }
  __syncthreads();
  int rg = tid >> 6, cg = tid & 63, lane = tid & 63;
  float acc[4][6] = {};
  for (int k = 0; k < DM; k += 4){
    float4 xv[4];
#pragma unroll
    for (int m = 0; m < 4; m++) xv[m] = *(const float4*)(su + (rg*4+m)*DM + k);
#pragma unroll
    for (int c = 0; c < 6; c++){
      float4 wv = *(const float4*)(w + (size_t)(cg*6+c)*DM + k);
#pragma unroll
      for (int m = 0; m < 4; m++)
        acc[m][c] += wv.x*xv[m].x + wv.y*xv[m].y + wv.z*xv[m].z + wv.w*xv[m].w;
    }
  }
#pragma unroll
  for (int c = 0; c < 6; c++){
    float bb = b[cg*6+c];
#pragma unroll
    for (int m = 0; m < 4; m++) uu[rg*4+m][cg*6+c] = acc[m][c] + bb;
  }
  __syncthreads();
#pragma unroll
  for (int q = 0; q < 4; q++){
    int r = rg*4 + q;
    float s1 = 0.f, s2 = 0.f;
#pragma unroll
    for (int t = 0; t < 6; t++){ float v = uu[r][t*64+lane]; s1 += v; s2 += v*v; }
#pragma unroll
    for (int o = 32; o > 0; o >>= 1){ s1 += __shfl_xor(s1,o); s2 += __shfl_xor(s2,o); }
    if (lane == 0){ float mean = s1/384.f; sm[r] = mean; sr[r] = rsqrtf(s2/384.f - mean*mean + LN_EPS); }
  }
  __syncthreads();
  for (int i = tid; i < 16*2*DM; i += 256){
    int r = i/(2*DM), c = i%(2*DM);
    float v = (uu[r][c]-sm[r])*sr[r]*lg[c]+lb[c];
    u2[(size_t)(n0+r)*DI + c] = v > 0.f ? v : 0.f;
  }
}

// ---------------- mlp2 + LN + residuals + final LN + attention score, fused ----------------
__global__ __launch_bounds__(256) void k_mlp2attn(const float* __restrict__ u2, const float* __restrict__ w,
    const float* __restrict__ b, const float* __restrict__ gg, const float* __restrict__ gb,
    const float* __restrict__ h2, const float* __restrict__ hres,
    const float* __restrict__ ng, const float* __restrict__ nb,
    const float* __restrict__ w1, const float* __restrict__ b1,
    const float* __restrict__ w2, const float* __restrict__ b2,
    float* __restrict__ hn2, float* __restrict__ ascore){
  __shared__ float su[16 * DI];
  __shared__ float go[16][DM];
  __shared__ float sm[16], sr[16];
  int n0 = blockIdx.x * 16, tid = threadIdx.x;
  for (int i = tid; i < 16 * DI / 4; i += 256)
    ((float4*)su)[i] = ((const float4*)(u2 + (size_t)n0*DI))[i];
  __syncthreads();
  int rg = tid >> 6, cg = tid & 63, lane = tid & 63;
  float acc[4][3] = {};
  for (int k = 0; k < DI; k += 4){
    float4 xv[4];
#pragma unroll
    for (int m = 0; m < 4; m++) xv[m] = *(const float4*)(su + (rg*4+m)*DI + k);
#pragma unroll
    for (int c = 0; c < 3; c++){
      float4 wv = *(const float4*)(w + (size_t)(cg*3+c)*DI + k);
#pragma unroll
      for (int m = 0; m < 4; m++)
        acc[m][c] += wv.x*xv[m].x + wv.y*xv[m].y + wv.z*xv[m].z + wv.w*xv[m].w;
    }
  }
#pragma unroll
  for (int c = 0; c < 3; c++){
    float bb = b[cg*3+c];
#pragma unroll
    for (int m = 0; m < 4; m++) go[rg*4+m][cg*3+c] = acc[m][c] + bb;
  }
  __syncthreads();
#pragma unroll
  for (int q = 0; q < 4; q++){
    int r = rg*4 + q;
    float v0 = go[r][lane], v1 = go[r][64+lane], v2 = go[r][128+lane];
    float s1 = v0+v1+v2, s2 = v0*v0+v1*v1+v2*v2;
#pragma unroll
    for (int o = 32; o > 0; o >>= 1){ s1 += __shfl_xor(s1,o); s2 += __shfl_xor(s2,o); }
    if (lane == 0){ float mean = s1/192.f; sm[r] = mean; sr[r] = rsqrtf(s2/192.f - mean*mean + LN_EPS); }
  }
  __syncthreads();
  for (int i = tid; i < 16*DM; i += 256){
    int r = i/DM, c = i%DM;
    float v = (go[r][c]-sm[r])*sr[r]*gg[c]+gb[c];
    v = v > 0.f ? v : 0.f;
    int n = n0 + r;
    go[r][c] = h2[(size_t)n*DM + c] + v + hres[(size_t)n*DM + c];
  }
  __syncthreads();
#pragma unroll
  for (int q = 0; q < 4; q++){
    int r = rg*4 + q;
    float v0 = go[r][lane], v1 = go[r][64+lane], v2 = go[r][128+lane];
    float s1 = v0+v1+v2, s2 = v0*v0+v1*v1+v2*v2;
#pragma unroll
    for (int o = 32; o > 0; o >>= 1){ s1 += __shfl_xor(s1,o); s2 += __shfl_xor(s2,o); }
    if (lane == 0){ float mean = s1/192.f; sm[r] = mean; sr[r] = rsqrtf(s2/192.f - mean*mean + LN_EPS); }
  }
  __syncthreads();
  float* sh = su;
  for (int i = tid; i < 16*DM; i += 256){
    int r = i/DM, c = i%DM;
    float v = (go[r][c]-sm[r])*sr[r]*ng[c]+nb[c];
    hn2[(size_t)(n0+r)*DM + c] = v;
    sh[r*DM + c] = v;
  }
  __syncthreads();
#pragma unroll
  for (int q = 0; q < 4; q++){
    int r = rg*4 + q;
    float a0 = b1[lane], a1 = b1[64+lane];
    for (int k = 0; k < DM; k += 4){
      float4 hv = *(const float4*)(sh + r*DM + k);
      float4 wa = *(const float4*)(w1 + (size_t)lane*DM + k);
      float4 wb = *(const float4*)(w1 + (size_t)(64+lane)*DM + k);
      a0 += wa.x*hv.x + wa.y*hv.y + wa.z*hv.z + wa.w*hv.w;
      a1 += wb.x*hv.x + wb.y*hv.y + wb.z*hv.z + wb.w*hv.w;
    }
    float t = tanhf(a0)*w2[lane] + tanhf(a1)*w2[64+lane];
#pragma unroll
    for (int o = 32; o > 0; o >>= 1) t += __shfl_xor(t, o);
    if (lane == 0) ascore[r + n0] = t + b2[0];
  }
}

// ---------------- softmax over a[N] ----------------
__global__ __launch_bounds__(1024) void k_softmax(float* __restrict__ a){
  int tid = threadIdx.x;
  __shared__ float rb[16];
  float mx = -1e30f;
  for (int i = tid; i < N; i += 1024) mx = fmaxf(mx, a[i]);
#pragma unroll
  for (int o = 32; o > 0; o >>= 1) mx = fmaxf(mx, __shfl_down(mx, o));
  if ((tid & 63) == 0) rb[tid >> 6] = mx;
  __syncthreads();
  float m = -1e30f;
  for (int i = 0; i < 16; i++) m = fmaxf(m, rb[i]);
  __syncthreads();
  float z = 0.f;
  for (int i = tid; i < N; i += 1024) z += __expf(a[i] - m);
#pragma unroll
  for (int o = 32; o > 0; o >>= 1) z += __shfl_down(z, o);
  if ((tid & 63) == 0) rb[tid >> 6] = z;
  __syncthreads();
  float Z = 0.f;
  for (int i = 0; i < 16; i++) Z += rb[i];
  float inv = 1.f / Z;
  for (int i = tid; i < N; i += 1024) a[i] = __expf(a[i] - m) * inv;
}

// ---------------- weighted pool ----------------
__global__ __launch_bounds__(192) void k_pool(const float* __restrict__ wgt, const float* __restrict__ hn2,
                                              float* __restrict__ pooled){
  int bidx = blockIdx.x, d = threadIdx.x;
  float acc = 0.f;
  for (int r = 0; r < 128; r++){
    int n = bidx * 128 + r;
    acc += wgt[n] * hn2[(size_t)n * DM + d];
  }
  atomicAdd(&pooled[d], acc);
}

// ---------------- head ----------------
__global__ __launch_bounds__(64) void k_head(const float* __restrict__ pooled, const float* __restrict__ hw,
                                             const float* __restrict__ hb, float* __restrict__ out){
  int tid = threadIdx.x;
  for (int c = 0; c < 2; c++){
    float s = 0.f;
    for (int d = tid; d < DM; d += 64) s += pooled[d] * hw[c * DM + d];
#pragma unroll
    for (int o = 32; o > 0; o >>= 1) s += __shfl_down(s, o);
    if (tid == 0) out[c] = s + hb[c];
  }
}

extern "C" void kernel_launch(void* const* d_in, const int* in_sizes, int n_in,
                              void* d_out, int out_size, void* d_ws, size_t ws_size,
                              hipStream_t stream){
  (void)in_sizes; (void)n_in; (void)out_size; (void)ws_size;
  const float* x        = (const float*)d_in[0];
  const int*   ei       = (const int*)d_in[1];
  const int*   perm_pre = (const int*)d_in[2];
  const int*   perm_post= (const int*)d_in[3];
  const int*   perm_lvl = (const int*)d_in[4];
  const float* ft_w     = (const float*)d_in[5];
  const float* ft_b     = (const float*)d_in[6];
  const float* ln1_g    = (const float*)d_in[7];
  const float* ln1_b    = (const float*)d_in[8];
  const float* in_proj_w= (const float*)d_in[9];
  const float* conv_w   = (const float*)d_in[10];
  const float* conv_b   = (const float*)d_in[11];
  const float* x_proj_w = (const float*)d_in[12];
  const float* dt_proj_w= (const float*)d_in[13];
  const float* dt_proj_b= (const float*)d_in[14];
  const float* A_log    = (const float*)d_in[15];
  const float* D_param  = (const float*)d_in[16];
  const float* out_proj_w=(const float*)d_in[17];
  const float* gnn_t    = (const float*)d_in[18];
  const float* mlp1_w   = (const float*)d_in[19];
  const float* mlp1_b   = (const float*)d_in[20];
  const float* mlp_ln_g = (const float*)d_in[21];
  const float* mlp_ln_b = (const float*)d_in[22];
  const float* mlp2_w   = (const float*)d_in[23];
  const float* mlp2_b   = (const float*)d_in[24];
  const float* gnn_g    = (const float*)d_in[25];
  const float* gnn_b    = (const float*)d_in[26];
  const float* norm_g   = (const float*)d_in[27];
  const float* norm_b   = (const float*)d_in[28];
  const float* attn1_w  = (const float*)d_in[29];
  const float* attn1_b  = (const float*)d_in[30];
  const float* attn2_w  = (const float*)d_in[31];
  const float* attn2_b  = (const float*)d_in[32];
  const float* head_w   = (const float*)d_in[33];
  const float* head_b   = (const float*)d_in[34];

  float* ws = (float*)d_ws;
  size_t off = 0;
  float* h      = ws + off; off += (size_t)N * DM;
  float* hn     = ws + off; off += (size_t)N * DM;
  float* xi     = ws + off; off += (size_t)N * DI;
  float* z      = ws + off; off += (size_t)N * DI;
  float* xc_all = ws + off; off += (size_t)NSEQ * N * DI;
  float* dtin   = ws + off; off += (size_t)NSEQ * N * DTR;
  float* Ball   = ws + off; off += (size_t)NSEQ * N * DS;
  float* Call   = ws + off; off += (size_t)NSEQ * N * DS;
  float* Pb     = ws + off; off += (size_t)NSEQ * NCHUNK * DI * DS;
  float* Fb     = ws + off; off += (size_t)NSEQ * NCHUNK * DI * DS;
  float* Hin    = ws + off; off += (size_t)NSEQ * NCHUNK * DI * DS;
  float* ysum   = ws + off; off += (size_t)N * DI;
  float* h2     = ws + off; off += (size_t)N * DM;
  float* den    = ws + off; off += (size_t)N * DM;
  float* aggrn  = ws + off; off += (size_t)N * DM;
  float* u2     = ws + off; off += (size_t)N * DI;
  float* hn2    = ws + off; off += (size_t)N * DM;
  float* ascore = ws + off; off += (size_t)N;
  float* pooled = ws + off; off += DM;

  k_init<<<dim3((N * DI + 255) / 256), dim3(256), 0, stream>>>(ysum, den, aggrn, pooled);
  k_ft<<<dim3(N / 16), dim3(256), 0, stream>>>(x, ft_w, ft_b, ln1_g, ln1_b, h, hn);
  k_inproj<<<dim3(N / 16), dim3(256), 0, stream>>>(hn, in_proj_w, xi, z);
  k_stagea<<<dim3(N / 64, NSEQ), dim3(512), 0, stream>>>(xi, perm_pre, perm_post, perm_lvl,
      conv_w, conv_b, x_proj_w, xc_all, dtin, Ball, Call);
  k_pass1<<<dim3(NCHUNK, NSEQ), dim3(384), 0, stream>>>(xc_all, dtin, Ball, A_log, dt_proj_w, dt_proj_b, Pb, Fb);
  k_pass2<<<dim3((NSEQ * DI * DS + 255) / 256), dim3(256), 0, stream>>>(Pb, Fb, Hin);
  k_pass3<<<dim3(NCHUNK, NSEQ), dim3(384), 0, stream>>>(xc_all, dtin, Ball, Call, A_log, dt_proj_w, dt_proj_b,
      D_param, Hin, perm_pre, perm_post, perm_lvl, ysum);
  k_outproj<<<dim3(N / 16), dim3(256), 0, stream>>>(ysum, z, out_proj_w, h2);
  k_edge<<<dim3((E_EDGES * DM + 255) / 256), dim3(256), 0, stream>>>(ei, h2, gnn_t, den, aggrn);
  k_mlp1<<<dim3(N / 16), dim3(256), 0, stream>>>(aggrn, den, h2, mlp1_w, mlp1_b, mlp_ln_g, mlp_ln_b, u2);
  k_mlp2attn<<<dim3(N / 16), dim3(256), 0, stream>>>(u2, mlp2_w, mlp2_b, gnn_g, gnn_b, h2, h,
      norm_g, norm_b, attn1_w, attn1_b, attn2_w, attn2_b, hn2, ascore);
  k_softmax<<<dim3(1), dim3(1024), 0, stream>>>(ascore);
  k_pool<<<dim3(N / 128), dim3(192), 0, stream>>>(ascore, hn2, pooled);
  k_head<<<dim3(1), dim3(64), 0, stream>>>(pooled, head_w, head_b, (float*)d_out);
}